// Round 1
// baseline (427.698 us; speedup 1.0000x reference)
//
#include <hip/hip_runtime.h>

#define B_TOT 16384
#define LAT   16
#define HID   256
#define STY   64
#define NS    10
#define RB    16      // rows per block
#define PAD   20      // padded floats per k-row in LDS (keeps float4 alignment, breaks bank stride)

// workspace layout (ints)
#define WS_CNT   0
#define WS_CUR   16
#define WS_SEG   32
#define WS_BLK   48            // blkoff[0..NS], 11 ints
#define WS_IDX   64
#define IDX_CAP  (B_TOT + NS*RB)
#define WS_INTS  (WS_IDX + IDX_CAP)

__global__ void k_init(int* __restrict__ ws) {
    int t = blockIdx.x * 256 + threadIdx.x;
    if (t < WS_INTS) ws[t] = 0;
}

__global__ void k_hist(const int* __restrict__ y, int* __restrict__ ws) {
    int b = blockIdx.x * 256 + threadIdx.x;
    if (b < B_TOT) atomicAdd(&ws[WS_CNT + y[b]], 1);
}

__global__ void k_off(int* __restrict__ ws) {
    if (threadIdx.x == 0) {
        int ab = 0, ae = 0;
        for (int s = 0; s < NS; ++s) {
            ws[WS_BLK + s] = ab;
            ws[WS_SEG + s] = ae;
            int c  = ws[WS_CNT + s];
            int nb = (c + RB - 1) / RB;
            ab += nb;
            ae += nb * RB;
        }
        ws[WS_BLK + NS] = ab;
    }
}

__global__ void k_scat(const int* __restrict__ y, int* __restrict__ ws) {
    int b = blockIdx.x * 256 + threadIdx.x;
    if (b < B_TOT) {
        int s = y[b];
        int p = atomicAdd(&ws[WS_CUR + s], 1);
        ws[WS_IDX + ws[WS_SEG + s] + p] = b;
    }
}

#define FMA16(wv_, hv_) do { \
    acc[0][0] = fmaf(hv_.x, wv_.x, acc[0][0]); \
    acc[0][1] = fmaf(hv_.y, wv_.x, acc[0][1]); \
    acc[0][2] = fmaf(hv_.z, wv_.x, acc[0][2]); \
    acc[0][3] = fmaf(hv_.w, wv_.x, acc[0][3]); \
    acc[1][0] = fmaf(hv_.x, wv_.y, acc[1][0]); \
    acc[1][1] = fmaf(hv_.y, wv_.y, acc[1][1]); \
    acc[1][2] = fmaf(hv_.z, wv_.y, acc[1][2]); \
    acc[1][3] = fmaf(hv_.w, wv_.y, acc[1][3]); \
    acc[2][0] = fmaf(hv_.x, wv_.z, acc[2][0]); \
    acc[2][1] = fmaf(hv_.y, wv_.z, acc[2][1]); \
    acc[2][2] = fmaf(hv_.z, wv_.z, acc[2][2]); \
    acc[2][3] = fmaf(hv_.w, wv_.z, acc[2][3]); \
    acc[3][0] = fmaf(hv_.x, wv_.w, acc[3][0]); \
    acc[3][1] = fmaf(hv_.y, wv_.w, acc[3][1]); \
    acc[3][2] = fmaf(hv_.z, wv_.w, acc[3][2]); \
    acc[3][3] = fmaf(hv_.w, wv_.w, acc[3][3]); \
} while (0)

__global__ __launch_bounds__(256, 3) void k_main(
    const float* __restrict__ z,
    const int* __restrict__ ws,
    const float* __restrict__ sw0, const float* __restrict__ sb0,
    const float* __restrict__ sw1, const float* __restrict__ sb1,
    const float* __restrict__ sw2, const float* __restrict__ sb2,
    const float* __restrict__ sw3, const float* __restrict__ sb3,
    const float* __restrict__ uw0, const float* __restrict__ ub0,
    const float* __restrict__ uw1, const float* __restrict__ ub1,
    const float* __restrict__ uw2, const float* __restrict__ ub2,
    const float* __restrict__ uw3, const float* __restrict__ ub3,
    float* __restrict__ out)
{
    const int bid = blockIdx.x;
    if (bid >= ws[WS_BLK + NS]) return;

    int s = 0;
    #pragma unroll
    for (int q = 0; q < NS - 1; ++q)
        if (bid >= ws[WS_BLK + q + 1]) s = q + 1;
    const int loc  = bid - ws[WS_BLK + s];
    int nval = ws[WS_CNT + s] - loc * RB;
    if (nval > RB) nval = RB;
    const int base = ws[WS_SEG + s] + loc * RB;

    __shared__ int bidx[RB];
    __shared__ __align__(16) float zt[LAT][PAD];
    __shared__ __align__(16) float ht[2][HID][PAD];

    const int t = threadIdx.x;
    if (t < RB) bidx[t] = ws[WS_IDX + base + t];
    __syncthreads();
    { // stage z tile, transposed: zt[k][r]
        int r = t & (RB - 1), k = t >> 4;
        zt[k][r] = z[bidx[r] * LAT + k];
    }
    __syncthreads();

    const int cg  = t & 63;       // column group 0..63
    const int wvi = t >> 6;       // wave id 0..3
    const int c0  = cg * 4;       // 4 output cols per thread
    const int r0  = wvi * 4;      // 4 rows per wave

    float acc[4][4];              // [ci][ri]

    // ---- layer 0: z[16] -> h[256] ----
    {
        float4 bv = *(const float4*)(sb0 + c0);
        #pragma unroll
        for (int ri = 0; ri < 4; ++ri) {
            acc[0][ri] = bv.x; acc[1][ri] = bv.y; acc[2][ri] = bv.z; acc[3][ri] = bv.w;
        }
        #pragma unroll
        for (int k = 0; k < LAT; ++k) {
            float4 wv = *(const float4*)(sw0 + k * HID + c0);
            float4 hv = *(const float4*)(&zt[k][r0]);
            FMA16(wv, hv);
        }
        #pragma unroll
        for (int ci = 0; ci < 4; ++ci) {
            float4 v;
            v.x = fmaxf(acc[ci][0], 0.f); v.y = fmaxf(acc[ci][1], 0.f);
            v.z = fmaxf(acc[ci][2], 0.f); v.w = fmaxf(acc[ci][3], 0.f);
            *(float4*)&ht[0][c0 + ci][r0] = v;
        }
    }
    __syncthreads();

    // ---- generic 256x256 layer: reads ht[src], writes ht[src^1] ----
    auto midlayer = [&](const float* __restrict__ W, const float* __restrict__ bs, int src) {
        float4 bv = *(const float4*)(bs + c0);
        #pragma unroll
        for (int ri = 0; ri < 4; ++ri) {
            acc[0][ri] = bv.x; acc[1][ri] = bv.y; acc[2][ri] = bv.z; acc[3][ri] = bv.w;
        }
        #pragma unroll 4
        for (int k = 0; k < HID; ++k) {
            float4 wv = *(const float4*)(W + k * HID + c0);
            float4 hv = *(const float4*)(&ht[src][k][r0]);
            FMA16(wv, hv);
        }
        const int dst = src ^ 1;
        #pragma unroll
        for (int ci = 0; ci < 4; ++ci) {
            float4 v;
            v.x = fmaxf(acc[ci][0], 0.f); v.y = fmaxf(acc[ci][1], 0.f);
            v.z = fmaxf(acc[ci][2], 0.f); v.w = fmaxf(acc[ci][3], 0.f);
            *(float4*)&ht[dst][c0 + ci][r0] = v;
        }
    };

    midlayer(sw1, sb1, 0); __syncthreads();
    midlayer(sw2, sb2, 1); __syncthreads();
    midlayer(sw3, sb3, 0); __syncthreads();   // trunk h3 -> ht[1]

    const long so = (long)s;
    midlayer(uw0 + so * HID * HID, ub0 + so * HID, 1); __syncthreads();
    midlayer(uw1 + so * HID * HID, ub1 + so * HID, 0); __syncthreads();
    midlayer(uw2 + so * HID * HID, ub2 + so * HID, 1); __syncthreads();  // -> ht[0]

    // ---- final layer: h[256] -> style[64], no relu, gathered write ----
    {
        const float* W  = uw3 + so * HID * STY;
        const float* bs = ub3 + so * STY;
        const int c64 = (t & 15) * 4;   // 16 col-groups x 4 cols
        const int rr  = t >> 4;         // 16 rows
        float4 bv = *(const float4*)(bs + c64);
        float a0 = bv.x, a1 = bv.y, a2 = bv.z, a3 = bv.w;
        #pragma unroll 4
        for (int k = 0; k < HID; ++k) {
            float4 wv = *(const float4*)(W + k * STY + c64);
            float  hv = ht[0][k][rr];
            a0 = fmaf(hv, wv.x, a0); a1 = fmaf(hv, wv.y, a1);
            a2 = fmaf(hv, wv.z, a2); a3 = fmaf(hv, wv.w, a3);
        }
        if (rr < nval) {
            float4 o = make_float4(a0, a1, a2, a3);
            *(float4*)(out + (long)bidx[rr] * STY + c64) = o;
        }
    }
}

extern "C" void kernel_launch(void* const* d_in, const int* in_sizes, int n_in,
                              void* d_out, int out_size, void* d_ws, size_t ws_size,
                              hipStream_t stream) {
    const float* z   = (const float*)d_in[0];
    const int*   y   = (const int*)  d_in[1];
    const float* sw0 = (const float*)d_in[2];  const float* sb0 = (const float*)d_in[3];
    const float* sw1 = (const float*)d_in[4];  const float* sb1 = (const float*)d_in[5];
    const float* sw2 = (const float*)d_in[6];  const float* sb2 = (const float*)d_in[7];
    const float* sw3 = (const float*)d_in[8];  const float* sb3 = (const float*)d_in[9];
    const float* uw0 = (const float*)d_in[10]; const float* ub0 = (const float*)d_in[11];
    const float* uw1 = (const float*)d_in[12]; const float* ub1 = (const float*)d_in[13];
    const float* uw2 = (const float*)d_in[14]; const float* ub2 = (const float*)d_in[15];
    const float* uw3 = (const float*)d_in[16]; const float* ub3 = (const float*)d_in[17];
    float* out = (float*)d_out;
    int*   ws  = (int*)d_ws;   // needs WS_INTS*4 ~= 66 KB of scratch

    k_init<<<(WS_INTS + 255) / 256, 256, 0, stream>>>(ws);
    k_hist<<<(B_TOT + 255) / 256, 256, 0, stream>>>(y, ws);
    k_off <<<1, 64, 0, stream>>>(ws);
    k_scat<<<(B_TOT + 255) / 256, 256, 0, stream>>>(y, ws);

    const int nblocks = B_TOT / RB + NS;
    k_main<<<nblocks, 256, 0, stream>>>(z, ws,
        sw0, sb0, sw1, sb1, sw2, sb2, sw3, sb3,
        uw0, ub0, uw1, ub1, uw2, ub2, uw3, ub3, out);
}

// Round 2
// 330.430 us; speedup vs baseline: 1.2944x; 1.2944x over previous
//
#include <hip/hip_runtime.h>

#define B_TOT 16384
#define LAT   16
#define HID   256
#define STY   64
#define NS    10
#define RB    16      // rows per block (fp32 fallback path)
#define RB64  64      // rows per block (bf16 MFMA path)
#define PAD   20

// workspace layout (ints)
#define WS_CNT   0
#define WS_CUR   16
#define WS_SEG   32
#define WS_BLK   48
#define WS_IDX   64
#define IDX_CAP  (B_TOT + NS*RB64)
#define WS_INTS  (WS_IDX + IDX_CAP)          // 17088 ints = 68352 B (256-mult)
#define WGT_OFF_EL (WS_INTS*2)               // ushort element offset = bytes/2
#define TOT_WEL  2334720                     // total bf16 weight elements
#define N_CHUNK  4560                        // TOT_WEL / 512

typedef __attribute__((ext_vector_type(8))) short bf16x8;
typedef __attribute__((ext_vector_type(4))) float f32x4;

static __device__ __forceinline__ ushort f2bf(float x) {
    union { float f; unsigned u; } c; c.f = x;
    unsigned u = c.u;
    unsigned r = u + 0x7FFFu + ((u >> 16) & 1u);   // RTNE
    return (ushort)(r >> 16);
}

__global__ void k_init(int* __restrict__ ws) {
    int t = blockIdx.x * 256 + threadIdx.x;
    if (t < WS_INTS) ws[t] = 0;
}

__global__ void k_hist(const int* __restrict__ y, int* __restrict__ ws) {
    int b = blockIdx.x * 256 + threadIdx.x;
    if (b < B_TOT) atomicAdd(&ws[WS_CNT + y[b]], 1);
}

__global__ void k_off(int* __restrict__ ws, int rb) {
    if (threadIdx.x == 0) {
        int ab = 0, ae = 0;
        for (int s = 0; s < NS; ++s) {
            ws[WS_BLK + s] = ab;
            ws[WS_SEG + s] = ae;
            int c  = ws[WS_CNT + s];
            int nb = (c + rb - 1) / rb;
            ab += nb;
            ae += nb * rb;
        }
        ws[WS_BLK + NS] = ab;
    }
}

__global__ void k_scat(const int* __restrict__ y, int* __restrict__ ws) {
    int b = blockIdx.x * 256 + threadIdx.x;
    if (b < B_TOT) {
        int s = y[b];
        int p = atomicAdd(&ws[WS_CUR + s], 1);
        ws[WS_IDX + ws[WS_SEG + s] + p] = b;
    }
}

// ---- convert fp32 weights -> bf16 in B-fragment-linear layout in ws ----
// chunk = one (layer, kb, nt): 64 lanes x 8 bf16 = 512 el = 1KB, stored at wgt + cid*512.
// B-frag mapping: lane l holds W[k = kb*32 + (l>>4)*8 + j][n = nt*16 + (l&15)], j=0..7.
__global__ __launch_bounds__(256) void k_conv(
    const float* __restrict__ sw0, const float* __restrict__ sw1,
    const float* __restrict__ sw2, const float* __restrict__ sw3,
    const float* __restrict__ uw0, const float* __restrict__ uw1,
    const float* __restrict__ uw2, const float* __restrict__ uw3,
    ushort* __restrict__ wgt)
{
    int wid = blockIdx.x * 4 + (threadIdx.x >> 6);
    if (wid >= N_CHUNK) return;
    int l = threadIdx.x & 63;

    const float* src; int Ksrc, N, kb, nt;
    if (wid < 16) {                    // L0: 16x256, zero-padded to K=32
        src = sw0; Ksrc = LAT; N = 256; kb = 0; nt = wid;
    } else if (wid < 400) {            // sw1..sw3
        int c = wid - 16; int ly = c >> 7; int r = c & 127;
        src = (ly == 0 ? sw1 : ly == 1 ? sw2 : sw3);
        Ksrc = 256; N = 256; kb = r >> 4; nt = r & 15;
    } else {                           // per-speaker branches
        int c = wid - 400; int s = c / 416; int r = c % 416;
        if (r < 384) {
            int ly = r >> 7; int rr = r & 127;
            src = (ly == 0 ? uw0 : ly == 1 ? uw1 : uw2) + (long)s * 65536;
            Ksrc = 256; N = 256; kb = rr >> 4; nt = rr & 15;
        } else {
            int rr = r - 384;
            src = uw3 + (long)s * 16384;
            Ksrc = 256; N = STY; kb = rr >> 2; nt = rr & 3;
        }
    }
    int k0 = kb * 32 + (l >> 4) * 8;
    int n  = nt * 16 + (l & 15);
    ushort v[8];
    #pragma unroll
    for (int j = 0; j < 8; ++j) {
        int k = k0 + j;
        float x = (k < Ksrc) ? src[(long)k * N + n] : 0.f;
        v[j] = f2bf(x);
    }
    uint4 o;
    o.x = (unsigned)v[0] | ((unsigned)v[1] << 16);
    o.y = (unsigned)v[2] | ((unsigned)v[3] << 16);
    o.z = (unsigned)v[4] | ((unsigned)v[5] << 16);
    o.w = (unsigned)v[6] | ((unsigned)v[7] << 16);
    *(uint4*)(wgt + (long)wid * 512 + l * 8) = o;
}

// ---- bf16 MFMA main kernel: 64 rows/block, 4 waves, wave w owns rows 16w..16w+15 ----
__global__ __launch_bounds__(256, 2) void k_main_bf(
    const float* __restrict__ z, const int* __restrict__ ws,
    const ushort* __restrict__ wgt,
    const float* __restrict__ sb0, const float* __restrict__ sb1,
    const float* __restrict__ sb2, const float* __restrict__ sb3,
    const float* __restrict__ ub0, const float* __restrict__ ub1,
    const float* __restrict__ ub2, const float* __restrict__ ub3,
    float* __restrict__ out)
{
    const int bid = blockIdx.x;
    if (bid >= ws[WS_BLK + NS]) return;

    int s = 0;
    #pragma unroll
    for (int q = 0; q < NS - 1; ++q)
        if (bid >= ws[WS_BLK + q + 1]) s = q + 1;
    const int loc  = bid - ws[WS_BLK + s];
    int nval = ws[WS_CNT + s] - loc * RB64;
    if (nval > RB64) nval = RB64;
    const int base = ws[WS_SEG + s] + loc * RB64;

    // A-frag subtiled activations: [buf][k>>3][row][k&7], bf16. 64KB.
    __shared__ ushort act[2][32][64][8];

    const int t = threadIdx.x, w = t >> 6, l = t & 63;
    const int lc = l & 15, lh = l >> 4;

    // stage z (each wave stages only its own 16 rows -> no barrier ever needed)
    {
        int row = w * 16 + (l >> 2), q = l & 3;
        int gb  = ws[WS_IDX + base + row];
        float4 zv = *(const float4*)(z + (long)gb * LAT + q * 4);
        ushort4 pv; pv.x = f2bf(zv.x); pv.y = f2bf(zv.y); pv.z = f2bf(zv.z); pv.w = f2bf(zv.w);
        *(ushort4*)&act[0][q >> 1][row][(q & 1) * 4] = pv;
        ushort4 zr; zr.x = zr.y = zr.z = zr.w = 0;
        *(ushort4*)&act[0][2 + (q >> 1)][row][(q & 1) * 4] = zr;   // zero-pad k=16..31
    }

    // ---- L0: act[0] -> act[1], KB=1 (K padded to 32) ----
    {
        f32x4 acc[16];
        #pragma unroll
        for (int nt = 0; nt < 16; ++nt) { float bv = sb0[nt * 16 + lc]; acc[nt] = (f32x4){bv, bv, bv, bv}; }
        bf16x8 a = *(const bf16x8*)&act[0][lh][w * 16 + lc][0];
        #pragma unroll
        for (int nt = 0; nt < 16; ++nt) {
            bf16x8 b = *(const bf16x8*)(wgt + (nt * 64 + l) * 8);
            acc[nt] = __builtin_amdgcn_mfma_f32_16x16x32_bf16(a, b, acc[nt], 0, 0, 0);
        }
        #pragma unroll
        for (int nt = 0; nt < 16; ++nt)
            #pragma unroll
            for (int rg = 0; rg < 4; ++rg) {
                float vv = fmaxf(acc[nt][rg], 0.f);
                int n = nt * 16 + lc, row = w * 16 + lh * 4 + rg;
                act[1][n >> 3][row][n & 7] = f2bf(vv);
            }
    }

    auto midlayer = [&](const ushort* __restrict__ wf, const float* __restrict__ bs, int src) {
        const int dst = src ^ 1;
        f32x4 acc[16];
        #pragma unroll
        for (int nt = 0; nt < 16; ++nt) { float bv = bs[nt * 16 + lc]; acc[nt] = (f32x4){bv, bv, bv, bv}; }
        #pragma unroll
        for (int kb = 0; kb < 8; ++kb) {
            bf16x8 a = *(const bf16x8*)&act[src][kb * 4 + lh][w * 16 + lc][0];
            #pragma unroll
            for (int nt = 0; nt < 16; ++nt) {
                bf16x8 b = *(const bf16x8*)(wf + ((kb * 16 + nt) * 64 + l) * 8);
                acc[nt] = __builtin_amdgcn_mfma_f32_16x16x32_bf16(a, b, acc[nt], 0, 0, 0);
            }
        }
        #pragma unroll
        for (int nt = 0; nt < 16; ++nt)
            #pragma unroll
            for (int rg = 0; rg < 4; ++rg) {
                float vv = fmaxf(acc[nt][rg], 0.f);
                int n = nt * 16 + lc, row = w * 16 + lh * 4 + rg;
                act[dst][n >> 3][row][n & 7] = f2bf(vv);
            }
    };

    midlayer(wgt + 8192,   sb1, 1);
    midlayer(wgt + 73728,  sb2, 0);
    midlayer(wgt + 139264, sb3, 1);
    const long sbse = 204800 + (long)s * 212992;
    midlayer(wgt + sbse,          ub0 + s * HID, 0);
    midlayer(wgt + sbse + 65536,  ub1 + s * HID, 1);
    midlayer(wgt + sbse + 131072, ub2 + s * HID, 0);

    // ---- final: act[1] x uw3 -> out (no relu), gathered fp32 write ----
    {
        const ushort* wf = wgt + sbse + 196608;
        const float*  bs = ub3 + s * STY;
        f32x4 acc[4];
        #pragma unroll
        for (int nt = 0; nt < 4; ++nt) { float bv = bs[nt * 16 + lc]; acc[nt] = (f32x4){bv, bv, bv, bv}; }
        #pragma unroll
        for (int kb = 0; kb < 8; ++kb) {
            bf16x8 a = *(const bf16x8*)&act[1][kb * 4 + lh][w * 16 + lc][0];
            #pragma unroll
            for (int nt = 0; nt < 4; ++nt) {
                bf16x8 b = *(const bf16x8*)(wf + ((kb * 4 + nt) * 64 + l) * 8);
                acc[nt] = __builtin_amdgcn_mfma_f32_16x16x32_bf16(a, b, acc[nt], 0, 0, 0);
            }
        }
        int rows[4], gbs[4];
        #pragma unroll
        for (int rg = 0; rg < 4; ++rg) {
            rows[rg] = w * 16 + lh * 4 + rg;
            gbs[rg]  = ws[WS_IDX + base + rows[rg]];
        }
        #pragma unroll
        for (int nt = 0; nt < 4; ++nt)
            #pragma unroll
            for (int rg = 0; rg < 4; ++rg)
                if (rows[rg] < nval)
                    out[(long)gbs[rg] * STY + nt * 16 + lc] = acc[nt][rg];
    }
}

// ================= fp32 fallback (round-1 kernel, RB=16) =================
#define FMA16(wv_, hv_) do { \
    acc[0][0] = fmaf(hv_.x, wv_.x, acc[0][0]); \
    acc[0][1] = fmaf(hv_.y, wv_.x, acc[0][1]); \
    acc[0][2] = fmaf(hv_.z, wv_.x, acc[0][2]); \
    acc[0][3] = fmaf(hv_.w, wv_.x, acc[0][3]); \
    acc[1][0] = fmaf(hv_.x, wv_.y, acc[1][0]); \
    acc[1][1] = fmaf(hv_.y, wv_.y, acc[1][1]); \
    acc[1][2] = fmaf(hv_.z, wv_.y, acc[1][2]); \
    acc[1][3] = fmaf(hv_.w, wv_.y, acc[1][3]); \
    acc[2][0] = fmaf(hv_.x, wv_.z, acc[2][0]); \
    acc[2][1] = fmaf(hv_.y, wv_.z, acc[2][1]); \
    acc[2][2] = fmaf(hv_.z, wv_.z, acc[2][2]); \
    acc[2][3] = fmaf(hv_.w, wv_.z, acc[2][3]); \
    acc[3][0] = fmaf(hv_.x, wv_.w, acc[3][0]); \
    acc[3][1] = fmaf(hv_.y, wv_.w, acc[3][1]); \
    acc[3][2] = fmaf(hv_.z, wv_.w, acc[3][2]); \
    acc[3][3] = fmaf(hv_.w, wv_.w, acc[3][3]); \
} while (0)

__global__ __launch_bounds__(256, 3) void k_main_f32(
    const float* __restrict__ z,
    const int* __restrict__ ws,
    const float* __restrict__ sw0, const float* __restrict__ sb0,
    const float* __restrict__ sw1, const float* __restrict__ sb1,
    const float* __restrict__ sw2, const float* __restrict__ sb2,
    const float* __restrict__ sw3, const float* __restrict__ sb3,
    const float* __restrict__ uw0, const float* __restrict__ ub0,
    const float* __restrict__ uw1, const float* __restrict__ ub1,
    const float* __restrict__ uw2, const float* __restrict__ ub2,
    const float* __restrict__ uw3, const float* __restrict__ ub3,
    float* __restrict__ out)
{
    const int bid = blockIdx.x;
    if (bid >= ws[WS_BLK + NS]) return;
    int s = 0;
    #pragma unroll
    for (int q = 0; q < NS - 1; ++q)
        if (bid >= ws[WS_BLK + q + 1]) s = q + 1;
    const int loc  = bid - ws[WS_BLK + s];
    int nval = ws[WS_CNT + s] - loc * RB;
    if (nval > RB) nval = RB;
    const int base = ws[WS_SEG + s] + loc * RB;

    __shared__ int bidx[RB];
    __shared__ __align__(16) float zt[LAT][PAD];
    __shared__ __align__(16) float ht[2][HID][PAD];

    const int t = threadIdx.x;
    if (t < RB) bidx[t] = ws[WS_IDX + base + t];
    __syncthreads();
    { int r = t & (RB - 1), k = t >> 4; zt[k][r] = z[bidx[r] * LAT + k]; }
    __syncthreads();

    const int cg = t & 63, wvi = t >> 6, c0 = cg * 4, r0 = wvi * 4;
    float acc[4][4];
    {
        float4 bv = *(const float4*)(sb0 + c0);
        #pragma unroll
        for (int ri = 0; ri < 4; ++ri) { acc[0][ri] = bv.x; acc[1][ri] = bv.y; acc[2][ri] = bv.z; acc[3][ri] = bv.w; }
        #pragma unroll
        for (int k = 0; k < LAT; ++k) {
            float4 wv = *(const float4*)(sw0 + k * HID + c0);
            float4 hv = *(const float4*)(&zt[k][r0]);
            FMA16(wv, hv);
        }
        #pragma unroll
        for (int ci = 0; ci < 4; ++ci) {
            float4 v;
            v.x = fmaxf(acc[ci][0], 0.f); v.y = fmaxf(acc[ci][1], 0.f);
            v.z = fmaxf(acc[ci][2], 0.f); v.w = fmaxf(acc[ci][3], 0.f);
            *(float4*)&ht[0][c0 + ci][r0] = v;
        }
    }
    __syncthreads();

    auto midlayer = [&](const float* __restrict__ W, const float* __restrict__ bs, int src) {
        float4 bv = *(const float4*)(bs + c0);
        #pragma unroll
        for (int ri = 0; ri < 4; ++ri) { acc[0][ri] = bv.x; acc[1][ri] = bv.y; acc[2][ri] = bv.z; acc[3][ri] = bv.w; }
        #pragma unroll 4
        for (int k = 0; k < HID; ++k) {
            float4 wv = *(const float4*)(W + k * HID + c0);
            float4 hv = *(const float4*)(&ht[src][k][r0]);
            FMA16(wv, hv);
        }
        const int dst = src ^ 1;
        #pragma unroll
        for (int ci = 0; ci < 4; ++ci) {
            float4 v;
            v.x = fmaxf(acc[ci][0], 0.f); v.y = fmaxf(acc[ci][1], 0.f);
            v.z = fmaxf(acc[ci][2], 0.f); v.w = fmaxf(acc[ci][3], 0.f);
            *(float4*)&ht[dst][c0 + ci][r0] = v;
        }
    };

    midlayer(sw1, sb1, 0); __syncthreads();
    midlayer(sw2, sb2, 1); __syncthreads();
    midlayer(sw3, sb3, 0); __syncthreads();
    const long so = (long)s;
    midlayer(uw0 + so * HID * HID, ub0 + so * HID, 1); __syncthreads();
    midlayer(uw1 + so * HID * HID, ub1 + so * HID, 0); __syncthreads();
    midlayer(uw2 + so * HID * HID, ub2 + so * HID, 1); __syncthreads();

    {
        const float* W  = uw3 + so * HID * STY;
        const float* bs = ub3 + so * STY;
        const int c64 = (t & 15) * 4, rr = t >> 4;
        float4 bv = *(const float4*)(bs + c64);
        float a0 = bv.x, a1 = bv.y, a2 = bv.z, a3 = bv.w;
        #pragma unroll 4
        for (int k = 0; k < HID; ++k) {
            float4 wv = *(const float4*)(W + k * STY + c64);
            float  hv = ht[0][k][rr];
            a0 = fmaf(hv, wv.x, a0); a1 = fmaf(hv, wv.y, a1);
            a2 = fmaf(hv, wv.z, a2); a3 = fmaf(hv, wv.w, a3);
        }
        if (rr < nval) *(float4*)(out + (long)bidx[rr] * STY + c64) = make_float4(a0, a1, a2, a3);
    }
}

extern "C" void kernel_launch(void* const* d_in, const int* in_sizes, int n_in,
                              void* d_out, int out_size, void* d_ws, size_t ws_size,
                              hipStream_t stream) {
    const float* z   = (const float*)d_in[0];
    const int*   y   = (const int*)  d_in[1];
    const float* sw0 = (const float*)d_in[2];  const float* sb0 = (const float*)d_in[3];
    const float* sw1 = (const float*)d_in[4];  const float* sb1 = (const float*)d_in[5];
    const float* sw2 = (const float*)d_in[6];  const float* sb2 = (const float*)d_in[7];
    const float* sw3 = (const float*)d_in[8];  const float* sb3 = (const float*)d_in[9];
    const float* uw0 = (const float*)d_in[10]; const float* ub0 = (const float*)d_in[11];
    const float* uw1 = (const float*)d_in[12]; const float* ub1 = (const float*)d_in[13];
    const float* uw2 = (const float*)d_in[14]; const float* ub2 = (const float*)d_in[15];
    const float* uw3 = (const float*)d_in[16]; const float* ub3 = (const float*)d_in[17];
    float* out = (float*)d_out;
    int*   ws  = (int*)d_ws;

    const size_t req = (size_t)WGT_OFF_EL * 2 + (size_t)TOT_WEL * 2;
    const bool bfp = (ws_size >= req);

    k_init<<<(WS_INTS + 255) / 256, 256, 0, stream>>>(ws);
    k_hist<<<(B_TOT + 255) / 256, 256, 0, stream>>>(y, ws);
    k_off <<<1, 64, 0, stream>>>(ws, bfp ? RB64 : RB);
    k_scat<<<(B_TOT + 255) / 256, 256, 0, stream>>>(y, ws);

    if (bfp) {
        ushort* wgt = (ushort*)d_ws + WGT_OFF_EL;
        k_conv<<<N_CHUNK / 4, 256, 0, stream>>>(sw0, sw1, sw2, sw3, uw0, uw1, uw2, uw3, wgt);
        const int nblocks = B_TOT / RB64 + NS;
        k_main_bf<<<nblocks, 256, 0, stream>>>(z, ws, wgt,
            sb0, sb1, sb2, sb3, ub0, ub1, ub2, ub3, out);
    } else {
        const int nblocks = B_TOT / RB + NS;
        k_main_f32<<<nblocks, 256, 0, stream>>>(z, ws,
            sw0, sb0, sw1, sb1, sw2, sb2, sw3, sb3,
            uw0, ub0, uw1, ub1, uw2, ub2, uw3, ub3, out);
    }
}

// Round 3
// 164.513 us; speedup vs baseline: 2.5998x; 2.0085x over previous
//
#include <hip/hip_runtime.h>

#define B_TOT 16384
#define LAT   16
#define HID   256
#define STY   64
#define NS    10
#define RB    16      // rows per block (fp32 fallback path)
#define RB64  64      // rows per block (bf16 MFMA path)
#define PAD   20

// workspace layout (ints)
#define WS_CNT   0
#define WS_CUR   16
#define WS_SEG   32
#define WS_BLK   48
#define WS_IDX   64
#define IDX_CAP  (B_TOT + NS*RB64)
#define WS_INTS  (WS_IDX + IDX_CAP)          // 17088 ints
#define WGT_OFF_EL (WS_INTS*2)               // ushort element offset = bytes/2
#define TOT_WEL  2334720                     // total bf16 weight elements
#define N_CHUNK  4560                        // TOT_WEL / 512

typedef __attribute__((ext_vector_type(8))) short bf16x8;
typedef __attribute__((ext_vector_type(4))) float f32x4;

static __device__ __forceinline__ ushort f2bf(float x) {
    union { float f; unsigned u; } c; c.f = x;
    unsigned u = c.u;
    unsigned r = u + 0x7FFFu + ((u >> 16) & 1u);   // RTNE
    return (ushort)(r >> 16);
}

__global__ void k_init(int* __restrict__ ws) {
    int t = blockIdx.x * 256 + threadIdx.x;
    if (t < WS_INTS) ws[t] = 0;
}

__global__ void k_hist(const int* __restrict__ y, int* __restrict__ ws) {
    int b = blockIdx.x * 256 + threadIdx.x;
    if (b < B_TOT) atomicAdd(&ws[WS_CNT + y[b]], 1);
}

// parallel prefix over 10 speakers: lane s sums counts < s (few cached loads)
__global__ void k_off(int* __restrict__ ws, int rb) {
    int sIdx = threadIdx.x;
    if (sIdx <= NS) {
        int ab = 0, ae = 0;
        for (int q = 0; q < sIdx; ++q) {
            int c  = ws[WS_CNT + q];
            int nb = (c + rb - 1) / rb;
            ab += nb; ae += nb * rb;
        }
        if (sIdx < NS) { ws[WS_BLK + sIdx] = ab; ws[WS_SEG + sIdx] = ae; }
        else           { ws[WS_BLK + NS]   = ab; }
    }
}

__global__ void k_scat(const int* __restrict__ y, int* __restrict__ ws) {
    int b = blockIdx.x * 256 + threadIdx.x;
    if (b < B_TOT) {
        int s = y[b];
        int p = atomicAdd(&ws[WS_CUR + s], 1);
        ws[WS_IDX + ws[WS_SEG + s] + p] = b;
    }
}

// ---- convert fp32 weights -> bf16 in B-fragment-linear layout in ws ----
// chunk = one (layer, kb, nt): 64 lanes x 8 bf16 = 512 el = 1KB at wgt + wid*512.
// B-frag mapping: lane l holds W[k = kb*32 + (l>>4)*8 + j][n = nt*16 + (l&15)], j=0..7.
// v3: coalesced float4 reads -> LDS tile -> fragment gather (was strided dword reads).
__global__ __launch_bounds__(256) void k_conv(
    const float* __restrict__ sw0, const float* __restrict__ sw1,
    const float* __restrict__ sw2, const float* __restrict__ sw3,
    const float* __restrict__ uw0, const float* __restrict__ uw1,
    const float* __restrict__ uw2, const float* __restrict__ uw3,
    ushort* __restrict__ wgt)
{
    __shared__ float tile[4][32][18];
    int wid = blockIdx.x * 4 + (threadIdx.x >> 6);   // N_CHUNK = 1140*4 exactly
    int wv  = threadIdx.x >> 6;
    int l   = threadIdx.x & 63;
    int lc  = l & 15, lh = l >> 4;

    const float* src; int Ksrc, N, kb, nt;
    if (wid < 16) {                    // L0: 16x256, zero-padded to K=32
        src = sw0; Ksrc = LAT; N = 256; kb = 0; nt = wid;
    } else if (wid < 400) {            // sw1..sw3
        int c = wid - 16; int ly = c >> 7; int r = c & 127;
        src = (ly == 0 ? sw1 : ly == 1 ? sw2 : sw3);
        Ksrc = 256; N = 256; kb = r >> 4; nt = r & 15;
    } else {                           // per-speaker branches
        int c = wid - 400; int s = c / 416; int r = c % 416;
        if (r < 384) {
            int ly = r >> 7; int rr = r & 127;
            src = (ly == 0 ? uw0 : ly == 1 ? uw1 : uw2) + (long)s * 65536;
            Ksrc = 256; N = 256; kb = rr >> 4; nt = rr & 15;
        } else {
            int rr = r - 384;
            src = uw3 + (long)s * 16384;
            Ksrc = 256; N = STY; kb = rr >> 2; nt = rr & 3;
        }
    }

    // coalesced load of the 32x16 fp32 sub-tile (two passes of 16 rows)
    #pragma unroll
    for (int it = 0; it < 2; ++it) {
        int r = it * 16 + (l >> 2);
        int k = kb * 32 + r;
        float4 v = make_float4(0.f, 0.f, 0.f, 0.f);
        if (k < Ksrc) v = *(const float4*)(src + (long)k * N + nt * 16 + (l & 3) * 4);
        int c = (l & 3) * 4;
        tile[wv][r][c] = v.x; tile[wv][r][c + 1] = v.y;
        tile[wv][r][c + 2] = v.z; tile[wv][r][c + 3] = v.w;
    }
    __syncthreads();

    ushort v[8];
    #pragma unroll
    for (int j = 0; j < 8; ++j) v[j] = f2bf(tile[wv][lh * 8 + j][lc]);
    uint4 o;
    o.x = (unsigned)v[0] | ((unsigned)v[1] << 16);
    o.y = (unsigned)v[2] | ((unsigned)v[3] << 16);
    o.z = (unsigned)v[4] | ((unsigned)v[5] << 16);
    o.w = (unsigned)v[6] | ((unsigned)v[7] << 16);
    *(uint4*)(wgt + (long)wid * 512 + l * 8) = o;
}

// ---- bf16 MFMA main kernel v3 ----
// 512 threads = 8 waves; 64 rows/block. Wave w: nt-quad wq=w&3, row-half wr=w>>2.
// Each B-frag load (1KB/wave, coalesced) feeds 2 MFMAs in-wave, 4 block-wide per kb;
// B-frags register-double-buffered across kb to hide L2/L3 latency.
__global__ __launch_bounds__(512, 2) void k_main_bf(
    const float* __restrict__ z, const int* __restrict__ ws,
    const ushort* __restrict__ wgt,
    const float* __restrict__ sb0, const float* __restrict__ sb1,
    const float* __restrict__ sb2, const float* __restrict__ sb3,
    const float* __restrict__ ub0, const float* __restrict__ ub1,
    const float* __restrict__ ub2, const float* __restrict__ ub3,
    float* __restrict__ out)
{
    const int bid = blockIdx.x;
    if (bid >= ws[WS_BLK + NS]) return;

    int s = 0;
    #pragma unroll
    for (int q = 0; q < NS - 1; ++q)
        if (bid >= ws[WS_BLK + q + 1]) s = q + 1;
    const int loc  = bid - ws[WS_BLK + s];
    int nval = ws[WS_CNT + s] - loc * RB64;
    if (nval > RB64) nval = RB64;
    const int base = ws[WS_SEG + s] + loc * RB64;

    // A-frag subtiled activations: [buf][k>>3][row][k&7], bf16. 64KB.
    __shared__ ushort act[2][32][64][8];

    const int t = threadIdx.x, w = t >> 6, l = t & 63;
    const int lc = l & 15, lh = l >> 4;
    const int wq = w & 3, wr = w >> 2;
    const int nt0 = wq * 4;          // this wave's 4 nt tiles
    const int r0  = wr * 32;         // this wave's 32 rows (2 row-tiles)

    // stage z transposed into A-frag layout (k 0..15 real, 16..31 zero)
    if (t < 256) {
        int row = t >> 2, q = t & 3;
        int gb  = ws[WS_IDX + base + row];
        float4 zv = *(const float4*)(z + (long)gb * LAT + q * 4);
        ushort4 pv; pv.x = f2bf(zv.x); pv.y = f2bf(zv.y); pv.z = f2bf(zv.z); pv.w = f2bf(zv.w);
        *(ushort4*)&act[0][q >> 1][row][(q & 1) * 4] = pv;
        ushort4 zr; zr.x = zr.y = zr.z = zr.w = 0;
        *(ushort4*)&act[0][2 + (q >> 1)][row][(q & 1) * 4] = zr;
    }
    __syncthreads();

    // ---- L0: act[0] -> act[1], single kb (K padded to 32) ----
    {
        f32x4 acc[4][2];
        #pragma unroll
        for (int q = 0; q < 4; ++q) {
            float bv = sb0[(nt0 + q) * 16 + lc];
            acc[q][0] = (f32x4){bv, bv, bv, bv};
            acc[q][1] = (f32x4){bv, bv, bv, bv};
        }
        bf16x8 A0 = *(const bf16x8*)&act[0][lh][r0 + lc][0];
        bf16x8 A1 = *(const bf16x8*)&act[0][lh][r0 + 16 + lc][0];
        #pragma unroll
        for (int q = 0; q < 4; ++q) {
            bf16x8 b = *(const bf16x8*)(wgt + ((nt0 + q) * 64 + l) * 8);
            acc[q][0] = __builtin_amdgcn_mfma_f32_16x16x32_bf16(A0, b, acc[q][0], 0, 0, 0);
            acc[q][1] = __builtin_amdgcn_mfma_f32_16x16x32_bf16(A1, b, acc[q][1], 0, 0, 0);
        }
        #pragma unroll
        for (int q = 0; q < 4; ++q) {
            int n = (nt0 + q) * 16 + lc;
            #pragma unroll
            for (int rt = 0; rt < 2; ++rt)
                #pragma unroll
                for (int rg = 0; rg < 4; ++rg) {
                    float vv = fmaxf(acc[q][rt][rg], 0.f);
                    act[1][n >> 3][r0 + rt * 16 + lh * 4 + rg][n & 7] = f2bf(vv);
                }
        }
    }
    __syncthreads();

    auto midlayer = [&](const ushort* __restrict__ wf, const float* __restrict__ bs, int src) {
        const int dst = src ^ 1;
        f32x4 acc[4][2];
        #pragma unroll
        for (int q = 0; q < 4; ++q) {
            float bv = bs[(nt0 + q) * 16 + lc];
            acc[q][0] = (f32x4){bv, bv, bv, bv};
            acc[q][1] = (f32x4){bv, bv, bv, bv};
        }
        bf16x8 Bc[4], Bn[4];
        #pragma unroll
        for (int q = 0; q < 4; ++q)
            Bc[q] = *(const bf16x8*)(wf + ((nt0 + q) * 64 + l) * 8);
        #pragma unroll
        for (int kb = 0; kb < 8; ++kb) {
            if (kb < 7) {
                #pragma unroll
                for (int q = 0; q < 4; ++q)
                    Bn[q] = *(const bf16x8*)(wf + (((kb + 1) * 16 + nt0 + q) * 64 + l) * 8);
            }
            bf16x8 A0 = *(const bf16x8*)&act[src][kb * 4 + lh][r0 + lc][0];
            bf16x8 A1 = *(const bf16x8*)&act[src][kb * 4 + lh][r0 + 16 + lc][0];
            #pragma unroll
            for (int q = 0; q < 4; ++q) {
                acc[q][0] = __builtin_amdgcn_mfma_f32_16x16x32_bf16(A0, Bc[q], acc[q][0], 0, 0, 0);
                acc[q][1] = __builtin_amdgcn_mfma_f32_16x16x32_bf16(A1, Bc[q], acc[q][1], 0, 0, 0);
            }
            #pragma unroll
            for (int q = 0; q < 4; ++q) Bc[q] = Bn[q];
        }
        #pragma unroll
        for (int q = 0; q < 4; ++q) {
            int n = (nt0 + q) * 16 + lc;
            #pragma unroll
            for (int rt = 0; rt < 2; ++rt)
                #pragma unroll
                for (int rg = 0; rg < 4; ++rg) {
                    float vv = fmaxf(acc[q][rt][rg], 0.f);
                    act[dst][n >> 3][r0 + rt * 16 + lh * 4 + rg][n & 7] = f2bf(vv);
                }
        }
        __syncthreads();
    };

    midlayer(wgt + 8192,   sb1, 1);
    midlayer(wgt + 73728,  sb2, 0);
    midlayer(wgt + 139264, sb3, 1);
    const long sbse = 204800 + (long)s * 212992;
    midlayer(wgt + sbse,          ub0 + s * HID, 0);
    midlayer(wgt + sbse + 65536,  ub1 + s * HID, 1);
    midlayer(wgt + sbse + 131072, ub2 + s * HID, 0);

    // ---- final: act[1] x uw3 -> out (no relu); wave wq owns nt=wq ----
    {
        const ushort* wf = wgt + sbse + 196608;
        const float*  bs = ub3 + s * STY;
        f32x4 acc[2];
        float bv = bs[wq * 16 + lc];
        acc[0] = (f32x4){bv, bv, bv, bv};
        acc[1] = (f32x4){bv, bv, bv, bv};
        bf16x8 Bc = *(const bf16x8*)(wf + (wq * 64 + l) * 8);
        bf16x8 Bn;
        #pragma unroll
        for (int kb = 0; kb < 8; ++kb) {
            if (kb < 7) Bn = *(const bf16x8*)(wf + (((kb + 1) * 4 + wq) * 64 + l) * 8);
            bf16x8 A0 = *(const bf16x8*)&act[1][kb * 4 + lh][r0 + lc][0];
            bf16x8 A1 = *(const bf16x8*)&act[1][kb * 4 + lh][r0 + 16 + lc][0];
            acc[0] = __builtin_amdgcn_mfma_f32_16x16x32_bf16(A0, Bc, acc[0], 0, 0, 0);
            acc[1] = __builtin_amdgcn_mfma_f32_16x16x32_bf16(A1, Bc, acc[1], 0, 0, 0);
            Bc = Bn;
        }
        #pragma unroll
        for (int rt = 0; rt < 2; ++rt)
            #pragma unroll
            for (int rg = 0; rg < 4; ++rg) {
                int row = r0 + rt * 16 + lh * 4 + rg;
                if (row < nval) {
                    int gb = ws[WS_IDX + base + row];
                    out[(long)gb * STY + wq * 16 + lc] = acc[rt][rg];
                }
            }
    }
}

// ================= fp32 fallback (round-1 kernel, RB=16) =================
#define FMA16(wv_, hv_) do { \
    acc[0][0] = fmaf(hv_.x, wv_.x, acc[0][0]); \
    acc[0][1] = fmaf(hv_.y, wv_.x, acc[0][1]); \
    acc[0][2] = fmaf(hv_.z, wv_.x, acc[0][2]); \
    acc[0][3] = fmaf(hv_.w, wv_.x, acc[0][3]); \
    acc[1][0] = fmaf(hv_.x, wv_.y, acc[1][0]); \
    acc[1][1] = fmaf(hv_.y, wv_.y, acc[1][1]); \
    acc[1][2] = fmaf(hv_.z, wv_.y, acc[1][2]); \
    acc[1][3] = fmaf(hv_.w, wv_.y, acc[1][3]); \
    acc[2][0] = fmaf(hv_.x, wv_.z, acc[2][0]); \
    acc[2][1] = fmaf(hv_.y, wv_.z, acc[2][1]); \
    acc[2][2] = fmaf(hv_.z, wv_.z, acc[2][2]); \
    acc[2][3] = fmaf(hv_.w, wv_.z, acc[2][3]); \
    acc[3][0] = fmaf(hv_.x, wv_.w, acc[3][0]); \
    acc[3][1] = fmaf(hv_.y, wv_.w, acc[3][1]); \
    acc[3][2] = fmaf(hv_.z, wv_.w, acc[3][2]); \
    acc[3][3] = fmaf(hv_.w, wv_.w, acc[3][3]); \
} while (0)

__global__ __launch_bounds__(256, 3) void k_main_f32(
    const float* __restrict__ z,
    const int* __restrict__ ws,
    const float* __restrict__ sw0, const float* __restrict__ sb0,
    const float* __restrict__ sw1, const float* __restrict__ sb1,
    const float* __restrict__ sw2, const float* __restrict__ sb2,
    const float* __restrict__ sw3, const float* __restrict__ sb3,
    const float* __restrict__ uw0, const float* __restrict__ ub0,
    const float* __restrict__ uw1, const float* __restrict__ ub1,
    const float* __restrict__ uw2, const float* __restrict__ ub2,
    const float* __restrict__ uw3, const float* __restrict__ ub3,
    float* __restrict__ out)
{
    const int bid = blockIdx.x;
    if (bid >= ws[WS_BLK + NS]) return;
    int s = 0;
    #pragma unroll
    for (int q = 0; q < NS - 1; ++q)
        if (bid >= ws[WS_BLK + q + 1]) s = q + 1;
    const int loc  = bid - ws[WS_BLK + s];
    int nval = ws[WS_CNT + s] - loc * RB;
    if (nval > RB) nval = RB;
    const int base = ws[WS_SEG + s] + loc * RB;

    __shared__ int bidx[RB];
    __shared__ __align__(16) float zt[LAT][PAD];
    __shared__ __align__(16) float ht[2][HID][PAD];

    const int t = threadIdx.x;
    if (t < RB) bidx[t] = ws[WS_IDX + base + t];
    __syncthreads();
    { int r = t & (RB - 1), k = t >> 4; zt[k][r] = z[bidx[r] * LAT + k]; }
    __syncthreads();

    const int cg = t & 63, wvi = t >> 6, c0 = cg * 4, r0 = wvi * 4;
    float acc[4][4];
    {
        float4 bv = *(const float4*)(sb0 + c0);
        #pragma unroll
        for (int ri = 0; ri < 4; ++ri) { acc[0][ri] = bv.x; acc[1][ri] = bv.y; acc[2][ri] = bv.z; acc[3][ri] = bv.w; }
        #pragma unroll
        for (int k = 0; k < LAT; ++k) {
            float4 wv = *(const float4*)(sw0 + k * HID + c0);
            float4 hv = *(const float4*)(&zt[k][r0]);
            FMA16(wv, hv);
        }
        #pragma unroll
        for (int ci = 0; ci < 4; ++ci) {
            float4 v;
            v.x = fmaxf(acc[ci][0], 0.f); v.y = fmaxf(acc[ci][1], 0.f);
            v.z = fmaxf(acc[ci][2], 0.f); v.w = fmaxf(acc[ci][3], 0.f);
            *(float4*)&ht[0][c0 + ci][r0] = v;
        }
    }
    __syncthreads();

    auto midlayer = [&](const float* __restrict__ W, const float* __restrict__ bs, int src) {
        float4 bv = *(const float4*)(bs + c0);
        #pragma unroll
        for (int ri = 0; ri < 4; ++ri) { acc[0][ri] = bv.x; acc[1][ri] = bv.y; acc[2][ri] = bv.z; acc[3][ri] = bv.w; }
        #pragma unroll 4
        for (int k = 0; k < HID; ++k) {
            float4 wv = *(const float4*)(W + k * HID + c0);
            float4 hv = *(const float4*)(&ht[src][k][r0]);
            FMA16(wv, hv);
        }
        const int dst = src ^ 1;
        #pragma unroll
        for (int ci = 0; ci < 4; ++ci) {
            float4 v;
            v.x = fmaxf(acc[ci][0], 0.f); v.y = fmaxf(acc[ci][1], 0.f);
            v.z = fmaxf(acc[ci][2], 0.f); v.w = fmaxf(acc[ci][3], 0.f);
            *(float4*)&ht[dst][c0 + ci][r0] = v;
        }
    };

    midlayer(sw1, sb1, 0); __syncthreads();
    midlayer(sw2, sb2, 1); __syncthreads();
    midlayer(sw3, sb3, 0); __syncthreads();
    const long so = (long)s;
    midlayer(uw0 + so * HID * HID, ub0 + so * HID, 1); __syncthreads();
    midlayer(uw1 + so * HID * HID, ub1 + so * HID, 0); __syncthreads();
    midlayer(uw2 + so * HID * HID, ub2 + so * HID, 1); __syncthreads();

    {
        const float* W  = uw3 + so * HID * STY;
        const float* bs = ub3 + so * STY;
        const int c64 = (t & 15) * 4, rr = t >> 4;
        float4 bv = *(const float4*)(bs + c64);
        float a0 = bv.x, a1 = bv.y, a2 = bv.z, a3 = bv.w;
        #pragma unroll 4
        for (int k = 0; k < HID; ++k) {
            float4 wv = *(const float4*)(W + k * STY + c64);
            float  hv = ht[0][k][rr];
            a0 = fmaf(hv, wv.x, a0); a1 = fmaf(hv, wv.y, a1);
            a2 = fmaf(hv, wv.z, a2); a3 = fmaf(hv, wv.w, a3);
        }
        if (rr < nval) *(float4*)(out + (long)bidx[rr] * STY + c64) = make_float4(a0, a1, a2, a3);
    }
}

extern "C" void kernel_launch(void* const* d_in, const int* in_sizes, int n_in,
                              void* d_out, int out_size, void* d_ws, size_t ws_size,
                              hipStream_t stream) {
    const float* z   = (const float*)d_in[0];
    const int*   y   = (const int*)  d_in[1];
    const float* sw0 = (const float*)d_in[2];  const float* sb0 = (const float*)d_in[3];
    const float* sw1 = (const float*)d_in[4];  const float* sb1 = (const float*)d_in[5];
    const float* sw2 = (const float*)d_in[6];  const float* sb2 = (const float*)d_in[7];
    const float* sw3 = (const float*)d_in[8];  const float* sb3 = (const float*)d_in[9];
    const float* uw0 = (const float*)d_in[10]; const float* ub0 = (const float*)d_in[11];
    const float* uw1 = (const float*)d_in[12]; const float* ub1 = (const float*)d_in[13];
    const float* uw2 = (const float*)d_in[14]; const float* ub2 = (const float*)d_in[15];
    const float* uw3 = (const float*)d_in[16]; const float* ub3 = (const float*)d_in[17];
    float* out = (float*)d_out;
    int*   ws  = (int*)d_ws;

    const size_t req = (size_t)WGT_OFF_EL * 2 + (size_t)TOT_WEL * 2;
    const bool bfp = (ws_size >= req);

    k_init<<<(WS_INTS + 255) / 256, 256, 0, stream>>>(ws);
    k_hist<<<(B_TOT + 255) / 256, 256, 0, stream>>>(y, ws);
    k_off <<<1, 64, 0, stream>>>(ws, bfp ? RB64 : RB);
    k_scat<<<(B_TOT + 255) / 256, 256, 0, stream>>>(y, ws);

    if (bfp) {
        ushort* wgt = (ushort*)d_ws + WGT_OFF_EL;
        k_conv<<<N_CHUNK / 4, 256, 0, stream>>>(sw0, sw1, sw2, sw3, uw0, uw1, uw2, uw3, wgt);
        const int nblocks = B_TOT / RB64 + NS;
        k_main_bf<<<nblocks, 512, 0, stream>>>(z, ws, wgt,
            sb0, sb1, sb2, sb3, ub0, ub1, ub2, ub3, out);
    } else {
        const int nblocks = B_TOT / RB + NS;
        k_main_f32<<<nblocks, 256, 0, stream>>>(z, ws,
            sw0, sb0, sw1, sb1, sw2, sb2, sw3, sb3,
            uw0, ub0, uw1, ub1, uw2, ub2, uw3, ub3, out);
    }
}

// Round 4
// 52.936 us; speedup vs baseline: 8.0795x; 3.1078x over previous
//
#include <hip/hip_runtime.h>

#define B_TOT 16384
#define LAT   16
#define HID   256
#define STY   64
#define NS    10
#define RB    16      // rows per block (fp32 fallback path)
#define RB64  64      // rows per block (bf16 MFMA path)
#define PAD   20
#define NBK   64      // histogram blocks = B_TOT/256

// workspace layout (ints)
#define WS_CNT   0                       // 10: total count per speaker
#define WS_SEG   16                      // 10: padded segment start per speaker
#define WS_BLK   32                      // 11: main-kernel block offsets
#define WS_BCNT  64                      // 64*10: per-block histogram
#define WS_BOFF  (WS_BCNT + NBK*NS)      // 64*10: absolute scatter offsets
#define WS_IDX   (WS_BOFF + NBK*NS)      // sorted row indices (+pad garbage, clamped)
#define IDX_CAP  (B_TOT + NS*RB64)
#define WS_INTS  (WS_IDX + IDX_CAP)
#define WGT_OFF_EL (((WS_INTS*4 + 255)/256)*128)   // ushort offset, 256B aligned
#define TOT_WEL  2334720                 // total bf16 weight elements
#define N_CHUNK  4560                    // TOT_WEL / 512

typedef __attribute__((ext_vector_type(8))) short bf16x8;
typedef __attribute__((ext_vector_type(4))) float f32x4;

static __device__ __forceinline__ ushort f2bf(float x) {
    union { float f; unsigned u; } c; c.f = x;
    unsigned u = c.u;
    unsigned r = u + 0x7FFFu + ((u >> 16) & 1u);   // RTNE
    return (ushort)(r >> 16);
}

// ---- prep 1: per-block histogram (no global atomics) ----
__global__ __launch_bounds__(256) void k_blkhist(const int* __restrict__ y, int* __restrict__ ws) {
    __shared__ int h[NS];
    int t = threadIdx.x;
    if (t < NS) h[t] = 0;
    __syncthreads();
    atomicAdd(&h[y[blockIdx.x * 256 + t]], 1);
    __syncthreads();
    if (t < NS) ws[WS_BCNT + blockIdx.x * NS + t] = h[t];
}

// ---- prep 2: scans + offset tables. 10 waves, wave s handles speaker s ----
__global__ __launch_bounds__(640) void k_off2(int* __restrict__ ws, int rb) {
    int s = threadIdx.x >> 6, b = threadIdx.x & 63;
    __shared__ int tot[NS];
    int c = (s < NS) ? ws[WS_BCNT + b * NS + s] : 0;
    int inc = c;
    #pragma unroll
    for (int o = 1; o < 64; o <<= 1) {
        int v = __shfl_up(inc, o, 64);
        if (b >= o) inc += v;
    }
    int excl = inc - c;
    if (s < NS && b == 63) tot[s] = inc;
    __syncthreads();
    if (s < NS) {
        int ab = 0, ae = 0;
        for (int q = 0; q < s; ++q) {
            int cq = tot[q];
            int nb = (cq + rb - 1) / rb;
            ab += nb; ae += nb * rb;
        }
        ws[WS_BOFF + b * NS + s] = ae + excl;
        if (b == 0) {
            ws[WS_CNT + s] = tot[s];
            ws[WS_SEG + s] = ae;
            ws[WS_BLK + s] = ab;
        }
    }
    if (threadIdx.x == 0) {
        int ab = 0;
        for (int q = 0; q < NS; ++q) ab += (tot[q] + rb - 1) / rb;
        ws[WS_BLK + NS] = ab;
    }
}

// ---- prep 3: scatter via LDS cursors (global-atomic-free) ----
__global__ __launch_bounds__(256) void k_scat2(const int* __restrict__ y, int* __restrict__ ws) {
    __shared__ int off[NS];
    int t = threadIdx.x;
    if (t < NS) off[t] = ws[WS_BOFF + blockIdx.x * NS + t];
    __syncthreads();
    int b = blockIdx.x * 256 + t;
    int p = atomicAdd(&off[y[b]], 1);
    ws[WS_IDX + p] = b;
}

// ---- convert fp32 weights -> bf16 in B-fragment-linear layout in ws ----
__global__ __launch_bounds__(256) void k_conv(
    const float* __restrict__ sw0, const float* __restrict__ sw1,
    const float* __restrict__ sw2, const float* __restrict__ sw3,
    const float* __restrict__ uw0, const float* __restrict__ uw1,
    const float* __restrict__ uw2, const float* __restrict__ uw3,
    ushort* __restrict__ wgt)
{
    __shared__ float tile[4][32][18];
    int wid = blockIdx.x * 4 + (threadIdx.x >> 6);
    int wv  = threadIdx.x >> 6;
    int l   = threadIdx.x & 63;
    int lc  = l & 15, lh = l >> 4;

    const float* src; int Ksrc, N, kb, nt;
    if (wid < 16) {
        src = sw0; Ksrc = LAT; N = 256; kb = 0; nt = wid;
    } else if (wid < 400) {
        int c = wid - 16; int ly = c >> 7; int r = c & 127;
        src = (ly == 0 ? sw1 : ly == 1 ? sw2 : sw3);
        Ksrc = 256; N = 256; kb = r >> 4; nt = r & 15;
    } else {
        int c = wid - 400; int s = c / 416; int r = c % 416;
        if (r < 384) {
            int ly = r >> 7; int rr = r & 127;
            src = (ly == 0 ? uw0 : ly == 1 ? uw1 : uw2) + (long)s * 65536;
            Ksrc = 256; N = 256; kb = rr >> 4; nt = rr & 15;
        } else {
            int rr = r - 384;
            src = uw3 + (long)s * 16384;
            Ksrc = 256; N = STY; kb = rr >> 2; nt = rr & 3;
        }
    }

    #pragma unroll
    for (int it = 0; it < 2; ++it) {
        int r = it * 16 + (l >> 2);
        int k = kb * 32 + r;
        float4 v = make_float4(0.f, 0.f, 0.f, 0.f);
        if (k < Ksrc) v = *(const float4*)(src + (long)k * N + nt * 16 + (l & 3) * 4);
        int c = (l & 3) * 4;
        tile[wv][r][c] = v.x; tile[wv][r][c + 1] = v.y;
        tile[wv][r][c + 2] = v.z; tile[wv][r][c + 3] = v.w;
    }
    __syncthreads();

    ushort v[8];
    #pragma unroll
    for (int j = 0; j < 8; ++j) v[j] = f2bf(tile[wv][lh * 8 + j][lc]);
    uint4 o;
    o.x = (unsigned)v[0] | ((unsigned)v[1] << 16);
    o.y = (unsigned)v[2] | ((unsigned)v[3] << 16);
    o.z = (unsigned)v[4] | ((unsigned)v[5] << 16);
    o.w = (unsigned)v[6] | ((unsigned)v[7] << 16);
    *(uint4*)(wgt + (long)wid * 512 + l * 8) = o;
}

// ---- bf16 MFMA main kernel: 512 threads = 8 waves; 64 rows/block ----
__global__ __launch_bounds__(512, 2) void k_main_bf(
    const float* __restrict__ z, const int* __restrict__ ws,
    const ushort* __restrict__ wgt,
    const float* __restrict__ sb0, const float* __restrict__ sb1,
    const float* __restrict__ sb2, const float* __restrict__ sb3,
    const float* __restrict__ ub0, const float* __restrict__ ub1,
    const float* __restrict__ ub2, const float* __restrict__ ub3,
    float* __restrict__ out)
{
    const int bid = blockIdx.x;
    if (bid >= ws[WS_BLK + NS]) return;

    int s = 0;
    #pragma unroll
    for (int q = 0; q < NS - 1; ++q)
        if (bid >= ws[WS_BLK + q + 1]) s = q + 1;
    const int loc  = bid - ws[WS_BLK + s];
    int nval = ws[WS_CNT + s] - loc * RB64;
    if (nval > RB64) nval = RB64;
    const int base = ws[WS_SEG + s] + loc * RB64;

    __shared__ ushort act[2][32][64][8];

    const int t = threadIdx.x, w = t >> 6, l = t & 63;
    const int lc = l & 15, lh = l >> 4;
    const int wq = w & 3, wr = w >> 2;
    const int nt0 = wq * 4;
    const int r0  = wr * 32;

    // stage z transposed into A-frag layout (k 0..15 real, 16..31 zero)
    if (t < 256) {
        int row = t >> 2, q = t & 3;
        int gb  = ws[WS_IDX + base + row];
        if (row >= nval) gb = 0;                       // pad slots hold garbage
        float4 zv = *(const float4*)(z + (long)gb * LAT + q * 4);
        ushort4 pv; pv.x = f2bf(zv.x); pv.y = f2bf(zv.y); pv.z = f2bf(zv.z); pv.w = f2bf(zv.w);
        *(ushort4*)&act[0][q >> 1][row][(q & 1) * 4] = pv;
        ushort4 zr; zr.x = zr.y = zr.z = zr.w = 0;
        *(ushort4*)&act[0][2 + (q >> 1)][row][(q & 1) * 4] = zr;
    }
    __syncthreads();

    // ---- L0 ----
    {
        f32x4 acc[4][2];
        #pragma unroll
        for (int q = 0; q < 4; ++q) {
            float bv = sb0[(nt0 + q) * 16 + lc];
            acc[q][0] = (f32x4){bv, bv, bv, bv};
            acc[q][1] = (f32x4){bv, bv, bv, bv};
        }
        bf16x8 A0 = *(const bf16x8*)&act[0][lh][r0 + lc][0];
        bf16x8 A1 = *(const bf16x8*)&act[0][lh][r0 + 16 + lc][0];
        #pragma unroll
        for (int q = 0; q < 4; ++q) {
            bf16x8 b = *(const bf16x8*)(wgt + ((nt0 + q) * 64 + l) * 8);
            acc[q][0] = __builtin_amdgcn_mfma_f32_16x16x32_bf16(A0, b, acc[q][0], 0, 0, 0);
            acc[q][1] = __builtin_amdgcn_mfma_f32_16x16x32_bf16(A1, b, acc[q][1], 0, 0, 0);
        }
        #pragma unroll
        for (int q = 0; q < 4; ++q) {
            int n = (nt0 + q) * 16 + lc;
            #pragma unroll
            for (int rt = 0; rt < 2; ++rt)
                #pragma unroll
                for (int rg = 0; rg < 4; ++rg) {
                    float vv = fmaxf(acc[q][rt][rg], 0.f);
                    act[1][n >> 3][r0 + rt * 16 + lh * 4 + rg][n & 7] = f2bf(vv);
                }
        }
    }
    __syncthreads();

    auto midlayer = [&](const ushort* __restrict__ wf, const float* __restrict__ bs, int src) {
        const int dst = src ^ 1;
        f32x4 acc[4][2];
        #pragma unroll
        for (int q = 0; q < 4; ++q) {
            float bv = bs[(nt0 + q) * 16 + lc];
            acc[q][0] = (f32x4){bv, bv, bv, bv};
            acc[q][1] = (f32x4){bv, bv, bv, bv};
        }
        bf16x8 Bc[4], Bn[4];
        #pragma unroll
        for (int q = 0; q < 4; ++q)
            Bc[q] = *(const bf16x8*)(wf + ((nt0 + q) * 64 + l) * 8);
        #pragma unroll
        for (int kb = 0; kb < 8; ++kb) {
            if (kb < 7) {
                #pragma unroll
                for (int q = 0; q < 4; ++q)
                    Bn[q] = *(const bf16x8*)(wf + (((kb + 1) * 16 + nt0 + q) * 64 + l) * 8);
            }
            bf16x8 A0 = *(const bf16x8*)&act[src][kb * 4 + lh][r0 + lc][0];
            bf16x8 A1 = *(const bf16x8*)&act[src][kb * 4 + lh][r0 + 16 + lc][0];
            #pragma unroll
            for (int q = 0; q < 4; ++q) {
                acc[q][0] = __builtin_amdgcn_mfma_f32_16x16x32_bf16(A0, Bc[q], acc[q][0], 0, 0, 0);
                acc[q][1] = __builtin_amdgcn_mfma_f32_16x16x32_bf16(A1, Bc[q], acc[q][1], 0, 0, 0);
            }
            #pragma unroll
            for (int q = 0; q < 4; ++q) Bc[q] = Bn[q];
        }
        #pragma unroll
        for (int q = 0; q < 4; ++q) {
            int n = (nt0 + q) * 16 + lc;
            #pragma unroll
            for (int rt = 0; rt < 2; ++rt)
                #pragma unroll
                for (int rg = 0; rg < 4; ++rg) {
                    float vv = fmaxf(acc[q][rt][rg], 0.f);
                    act[dst][n >> 3][r0 + rt * 16 + lh * 4 + rg][n & 7] = f2bf(vv);
                }
        }
        __syncthreads();
    };

    midlayer(wgt + 8192,   sb1, 1);
    midlayer(wgt + 73728,  sb2, 0);
    midlayer(wgt + 139264, sb3, 1);
    const long sbse = 204800 + (long)s * 212992;
    midlayer(wgt + sbse,          ub0 + s * HID, 0);
    midlayer(wgt + sbse + 65536,  ub1 + s * HID, 1);
    midlayer(wgt + sbse + 131072, ub2 + s * HID, 0);

    // ---- final layer ----
    {
        const ushort* wf = wgt + sbse + 196608;
        const float*  bs = ub3 + s * STY;
        f32x4 acc[2];
        float bv = bs[wq * 16 + lc];
        acc[0] = (f32x4){bv, bv, bv, bv};
        acc[1] = (f32x4){bv, bv, bv, bv};
        bf16x8 Bc = *(const bf16x8*)(wf + (wq * 64 + l) * 8);
        bf16x8 Bn;
        #pragma unroll
        for (int kb = 0; kb < 8; ++kb) {
            if (kb < 7) Bn = *(const bf16x8*)(wf + (((kb + 1) * 4 + wq) * 64 + l) * 8);
            bf16x8 A0 = *(const bf16x8*)&act[1][kb * 4 + lh][r0 + lc][0];
            bf16x8 A1 = *(const bf16x8*)&act[1][kb * 4 + lh][r0 + 16 + lc][0];
            acc[0] = __builtin_amdgcn_mfma_f32_16x16x32_bf16(A0, Bc, acc[0], 0, 0, 0);
            acc[1] = __builtin_amdgcn_mfma_f32_16x16x32_bf16(A1, Bc, acc[1], 0, 0, 0);
            Bc = Bn;
        }
        #pragma unroll
        for (int rt = 0; rt < 2; ++rt)
            #pragma unroll
            for (int rg = 0; rg < 4; ++rg) {
                int row = r0 + rt * 16 + lh * 4 + rg;
                if (row < nval) {
                    int gb = ws[WS_IDX + base + row];
                    out[(long)gb * STY + wq * 16 + lc] = acc[rt][rg];
                }
            }
    }
}

// ================= fp32 fallback (RB=16) =================
#define FMA16(wv_, hv_) do { \
    acc[0][0] = fmaf(hv_.x, wv_.x, acc[0][0]); \
    acc[0][1] = fmaf(hv_.y, wv_.x, acc[0][1]); \
    acc[0][2] = fmaf(hv_.z, wv_.x, acc[0][2]); \
    acc[0][3] = fmaf(hv_.w, wv_.x, acc[0][3]); \
    acc[1][0] = fmaf(hv_.x, wv_.y, acc[1][0]); \
    acc[1][1] = fmaf(hv_.y, wv_.y, acc[1][1]); \
    acc[1][2] = fmaf(hv_.z, wv_.y, acc[1][2]); \
    acc[1][3] = fmaf(hv_.w, wv_.y, acc[1][3]); \
    acc[2][0] = fmaf(hv_.x, wv_.z, acc[2][0]); \
    acc[2][1] = fmaf(hv_.y, wv_.z, acc[2][1]); \
    acc[2][2] = fmaf(hv_.z, wv_.z, acc[2][2]); \
    acc[2][3] = fmaf(hv_.w, wv_.z, acc[2][3]); \
    acc[3][0] = fmaf(hv_.x, wv_.w, acc[3][0]); \
    acc[3][1] = fmaf(hv_.y, wv_.w, acc[3][1]); \
    acc[3][2] = fmaf(hv_.z, wv_.w, acc[3][2]); \
    acc[3][3] = fmaf(hv_.w, wv_.w, acc[3][3]); \
} while (0)

__global__ __launch_bounds__(256, 3) void k_main_f32(
    const float* __restrict__ z,
    const int* __restrict__ ws,
    const float* __restrict__ sw0, const float* __restrict__ sb0,
    const float* __restrict__ sw1, const float* __restrict__ sb1,
    const float* __restrict__ sw2, const float* __restrict__ sb2,
    const float* __restrict__ sw3, const float* __restrict__ sb3,
    const float* __restrict__ uw0, const float* __restrict__ ub0,
    const float* __restrict__ uw1, const float* __restrict__ ub1,
    const float* __restrict__ uw2, const float* __restrict__ ub2,
    const float* __restrict__ uw3, const float* __restrict__ ub3,
    float* __restrict__ out)
{
    const int bid = blockIdx.x;
    if (bid >= ws[WS_BLK + NS]) return;
    int s = 0;
    #pragma unroll
    for (int q = 0; q < NS - 1; ++q)
        if (bid >= ws[WS_BLK + q + 1]) s = q + 1;
    const int loc  = bid - ws[WS_BLK + s];
    int nval = ws[WS_CNT + s] - loc * RB;
    if (nval > RB) nval = RB;
    const int base = ws[WS_SEG + s] + loc * RB;

    __shared__ int bidx[RB];
    __shared__ __align__(16) float zt[LAT][PAD];
    __shared__ __align__(16) float ht[2][HID][PAD];

    const int t = threadIdx.x;
    if (t < RB) {
        int gb = ws[WS_IDX + base + t];
        bidx[t] = (t < nval) ? gb : 0;
    }
    __syncthreads();
    { int r = t & (RB - 1), k = t >> 4; zt[k][r] = z[bidx[r] * LAT + k]; }
    __syncthreads();

    const int cg = t & 63, wvi = t >> 6, c0 = cg * 4, r0 = wvi * 4;
    float acc[4][4];
    {
        float4 bv = *(const float4*)(sb0 + c0);
        #pragma unroll
        for (int ri = 0; ri < 4; ++ri) { acc[0][ri] = bv.x; acc[1][ri] = bv.y; acc[2][ri] = bv.z; acc[3][ri] = bv.w; }
        #pragma unroll
        for (int k = 0; k < LAT; ++k) {
            float4 wv = *(const float4*)(sw0 + k * HID + c0);
            float4 hv = *(const float4*)(&zt[k][r0]);
            FMA16(wv, hv);
        }
        #pragma unroll
        for (int ci = 0; ci < 4; ++ci) {
            float4 v;
            v.x = fmaxf(acc[ci][0], 0.f); v.y = fmaxf(acc[ci][1], 0.f);
            v.z = fmaxf(acc[ci][2], 0.f); v.w = fmaxf(acc[ci][3], 0.f);
            *(float4*)&ht[0][c0 + ci][r0] = v;
        }
    }
    __syncthreads();

    auto midlayer = [&](const float* __restrict__ W, const float* __restrict__ bs, int src) {
        float4 bv = *(const float4*)(bs + c0);
        #pragma unroll
        for (int ri = 0; ri < 4; ++ri) { acc[0][ri] = bv.x; acc[1][ri] = bv.y; acc[2][ri] = bv.z; acc[3][ri] = bv.w; }
        #pragma unroll 4
        for (int k = 0; k < HID; ++k) {
            float4 wv = *(const float4*)(W + k * HID + c0);
            float4 hv = *(const float4*)(&ht[src][k][r0]);
            FMA16(wv, hv);
        }
        const int dst = src ^ 1;
        #pragma unroll
        for (int ci = 0; ci < 4; ++ci) {
            float4 v;
            v.x = fmaxf(acc[ci][0], 0.f); v.y = fmaxf(acc[ci][1], 0.f);
            v.z = fmaxf(acc[ci][2], 0.f); v.w = fmaxf(acc[ci][3], 0.f);
            *(float4*)&ht[dst][c0 + ci][r0] = v;
        }
    };

    midlayer(sw1, sb1, 0); __syncthreads();
    midlayer(sw2, sb2, 1); __syncthreads();
    midlayer(sw3, sb3, 0); __syncthreads();
    const long so = (long)s;
    midlayer(uw0 + so * HID * HID, ub0 + so * HID, 1); __syncthreads();
    midlayer(uw1 + so * HID * HID, ub1 + so * HID, 0); __syncthreads();
    midlayer(uw2 + so * HID * HID, ub2 + so * HID, 1); __syncthreads();

    {
        const float* W  = uw3 + so * HID * STY;
        const float* bs = ub3 + so * STY;
        const int c64 = (t & 15) * 4, rr = t >> 4;
        float4 bv = *(const float4*)(bs + c64);
        float a0 = bv.x, a1 = bv.y, a2 = bv.z, a3 = bv.w;
        #pragma unroll 4
        for (int k = 0; k < HID; ++k) {
            float4 wv = *(const float4*)(W + k * STY + c64);
            float  hv = ht[0][k][rr];
            a0 = fmaf(hv, wv.x, a0); a1 = fmaf(hv, wv.y, a1);
            a2 = fmaf(hv, wv.z, a2); a3 = fmaf(hv, wv.w, a3);
        }
        if (rr < nval) *(float4*)(out + (long)bidx[rr] * STY + c64) = make_float4(a0, a1, a2, a3);
    }
}

extern "C" void kernel_launch(void* const* d_in, const int* in_sizes, int n_in,
                              void* d_out, int out_size, void* d_ws, size_t ws_size,
                              hipStream_t stream) {
    const float* z   = (const float*)d_in[0];
    const int*   y   = (const int*)  d_in[1];
    const float* sw0 = (const float*)d_in[2];  const float* sb0 = (const float*)d_in[3];
    const float* sw1 = (const float*)d_in[4];  const float* sb1 = (const float*)d_in[5];
    const float* sw2 = (const float*)d_in[6];  const float* sb2 = (const float*)d_in[7];
    const float* sw3 = (const float*)d_in[8];  const float* sb3 = (const float*)d_in[9];
    const float* uw0 = (const float*)d_in[10]; const float* ub0 = (const float*)d_in[11];
    const float* uw1 = (const float*)d_in[12]; const float* ub1 = (const float*)d_in[13];
    const float* uw2 = (const float*)d_in[14]; const float* ub2 = (const float*)d_in[15];
    const float* uw3 = (const float*)d_in[16]; const float* ub3 = (const float*)d_in[17];
    float* out = (float*)d_out;
    int*   ws  = (int*)d_ws;

    const size_t req = (size_t)WGT_OFF_EL * 2 + (size_t)TOT_WEL * 2;
    const bool bfp = (ws_size >= req);
    const int  rb  = bfp ? RB64 : RB;

    k_blkhist<<<NBK, 256, 0, stream>>>(y, ws);
    k_off2   <<<1, 640, 0, stream>>>(ws, rb);
    k_scat2  <<<NBK, 256, 0, stream>>>(y, ws);

    if (bfp) {
        ushort* wgt = (ushort*)d_ws + WGT_OFF_EL;
        k_conv<<<N_CHUNK / 4, 256, 0, stream>>>(sw0, sw1, sw2, sw3, uw0, uw1, uw2, uw3, wgt);
        const int nblocks = B_TOT / RB64 + NS;
        k_main_bf<<<nblocks, 512, 0, stream>>>(z, ws, wgt,
            sb0, sb1, sb2, sb3, ub0, ub1, ub2, ub3, out);
    } else {
        const int nblocks = B_TOT / RB + NS;
        k_main_f32<<<nblocks, 256, 0, stream>>>(z, ws,
            sw0, sb0, sw1, sb1, sw2, sb2, sw3, sb3,
            uw0, ub0, uw1, ub1, uw2, ub2, uw3, ub3, out);
    }
}

// Round 5
// 46.507 us; speedup vs baseline: 9.1963x; 1.1382x over previous
//
#include <hip/hip_runtime.h>

#define B_TOT 16384
#define LAT   16
#define HID   256
#define STY   64
#define NS    10
#define RB    16      // rows per block (fp32 fallback path)
#define RB64  64      // rows per block (bf16 MFMA path)
#define PAD   20
#define NBK   64      // histogram blocks = B_TOT/256

// workspace layout (ints)
#define WS_CNT   0                       // 10: total count per speaker
#define WS_SEG   16                      // 10: padded segment start per speaker
#define WS_BLK   32                      // 11: main-kernel block offsets
#define WS_BCNT  64                      // 64*10: per-block histogram
#define WS_BOFF  (WS_BCNT + NBK*NS)      // 64*10: absolute scatter offsets
#define WS_IDX   (WS_BOFF + NBK*NS)      // sorted row indices (+pad garbage, clamped)
#define IDX_CAP  (B_TOT + NS*RB64)
#define WS_INTS  (WS_IDX + IDX_CAP)
#define WGT_OFF_EL (((WS_INTS*4 + 255)/256)*128)   // ushort offset, 256B aligned
#define TOT_WEL  2334720                 // total bf16 weight elements
#define N_CHUNK  4560                    // TOT_WEL / 512

typedef __attribute__((ext_vector_type(8))) short bf16x8;
typedef __attribute__((ext_vector_type(4))) float f32x4;

static __device__ __forceinline__ ushort f2bf(float x) {
    union { float f; unsigned u; } c; c.f = x;
    unsigned u = c.u;
    unsigned r = u + 0x7FFFu + ((u >> 16) & 1u);   // RTNE
    return (ushort)(r >> 16);
}

// ---- prep 1: per-block histogram (no global atomics) ----
__global__ __launch_bounds__(256) void k_blkhist(const int* __restrict__ y, int* __restrict__ ws) {
    __shared__ int h[NS];
    int t = threadIdx.x;
    if (t < NS) h[t] = 0;
    __syncthreads();
    atomicAdd(&h[y[blockIdx.x * 256 + t]], 1);
    __syncthreads();
    if (t < NS) ws[WS_BCNT + blockIdx.x * NS + t] = h[t];
}

// ---- prep 2: scans + offset tables. 10 waves, wave s handles speaker s ----
__global__ __launch_bounds__(640) void k_off2(int* __restrict__ ws, int rb) {
    int s = threadIdx.x >> 6, b = threadIdx.x & 63;
    __shared__ int tot[NS];
    int c = (s < NS) ? ws[WS_BCNT + b * NS + s] : 0;
    int inc = c;
    #pragma unroll
    for (int o = 1; o < 64; o <<= 1) {
        int v = __shfl_up(inc, o, 64);
        if (b >= o) inc += v;
    }
    int excl = inc - c;
    if (s < NS && b == 63) tot[s] = inc;
    __syncthreads();
    if (s < NS) {
        int ab = 0, ae = 0;
        for (int q = 0; q < s; ++q) {
            int cq = tot[q];
            int nb = (cq + rb - 1) / rb;
            ab += nb; ae += nb * rb;
        }
        ws[WS_BOFF + b * NS + s] = ae + excl;
        if (b == 0) {
            ws[WS_CNT + s] = tot[s];
            ws[WS_SEG + s] = ae;
            ws[WS_BLK + s] = ab;
        }
    }
    if (threadIdx.x == 0) {
        int ab = 0;
        for (int q = 0; q < NS; ++q) ab += (tot[q] + rb - 1) / rb;
        ws[WS_BLK + NS] = ab;
    }
}

// ---- prep 3: scatter via LDS cursors (global-atomic-free) ----
__global__ __launch_bounds__(256) void k_scat2(const int* __restrict__ y, int* __restrict__ ws) {
    __shared__ int off[NS];
    int t = threadIdx.x;
    if (t < NS) off[t] = ws[WS_BOFF + blockIdx.x * NS + t];
    __syncthreads();
    int b = blockIdx.x * 256 + t;
    int p = atomicAdd(&off[y[b]], 1);
    ws[WS_IDX + p] = b;
}

// ---- convert fp32 weights -> bf16 in fragment-linear layout in ws ----
// chunk = one (layer, kb, nt): lane l holds W[k=kb*32+(l>>4)*8+j][n=nt*16+(l&15)]
__global__ __launch_bounds__(256) void k_conv(
    const float* __restrict__ sw0, const float* __restrict__ sw1,
    const float* __restrict__ sw2, const float* __restrict__ sw3,
    const float* __restrict__ uw0, const float* __restrict__ uw1,
    const float* __restrict__ uw2, const float* __restrict__ uw3,
    ushort* __restrict__ wgt)
{
    __shared__ float tile[4][32][18];
    int wid = blockIdx.x * 4 + (threadIdx.x >> 6);
    int wv  = threadIdx.x >> 6;
    int l   = threadIdx.x & 63;
    int lc  = l & 15, lh = l >> 4;

    const float* src; int Ksrc, N, kb, nt;
    if (wid < 16) {
        src = sw0; Ksrc = LAT; N = 256; kb = 0; nt = wid;
    } else if (wid < 400) {
        int c = wid - 16; int ly = c >> 7; int r = c & 127;
        src = (ly == 0 ? sw1 : ly == 1 ? sw2 : sw3);
        Ksrc = 256; N = 256; kb = r >> 4; nt = r & 15;
    } else {
        int c = wid - 400; int s = c / 416; int r = c % 416;
        if (r < 384) {
            int ly = r >> 7; int rr = r & 127;
            src = (ly == 0 ? uw0 : ly == 1 ? uw1 : uw2) + (long)s * 65536;
            Ksrc = 256; N = 256; kb = rr >> 4; nt = rr & 15;
        } else {
            int rr = r - 384;
            src = uw3 + (long)s * 16384;
            Ksrc = 256; N = STY; kb = rr >> 2; nt = rr & 3;
        }
    }

    #pragma unroll
    for (int it = 0; it < 2; ++it) {
        int r = it * 16 + (l >> 2);
        int k = kb * 32 + r;
        float4 v = make_float4(0.f, 0.f, 0.f, 0.f);
        if (k < Ksrc) v = *(const float4*)(src + (long)k * N + nt * 16 + (l & 3) * 4);
        int c = (l & 3) * 4;
        tile[wv][r][c] = v.x; tile[wv][r][c + 1] = v.y;
        tile[wv][r][c + 2] = v.z; tile[wv][r][c + 3] = v.w;
    }
    __syncthreads();

    ushort v[8];
    #pragma unroll
    for (int j = 0; j < 8; ++j) v[j] = f2bf(tile[wv][lh * 8 + j][lc]);
    uint4 o;
    o.x = (unsigned)v[0] | ((unsigned)v[1] << 16);
    o.y = (unsigned)v[2] | ((unsigned)v[3] << 16);
    o.z = (unsigned)v[4] | ((unsigned)v[5] << 16);
    o.w = (unsigned)v[6] | ((unsigned)v[7] << 16);
    *(uint4*)(wgt + (long)wid * 512 + l * 8) = o;
}

// ---- bf16 MFMA main kernel v5 ----
// 512 threads = 8 waves; 64 rows/block. nt-split-8: wave w owns nt {2w,2w+1},
// all 4 row-tiles -> every W-frag loaded once per block (128 KB/layer).
// Operand-swapped MFMA: acc = mfma(Wfrag, actfrag) gives lane = sample-row,
// regs = 4 consecutive out-channels -> float4 bias, b64 LDS writes, float4 out.
__global__ __launch_bounds__(512, 4) void k_main_bf(
    const float* __restrict__ z, const int* __restrict__ ws,
    const ushort* __restrict__ wgt,
    const float* __restrict__ sb0, const float* __restrict__ sb1,
    const float* __restrict__ sb2, const float* __restrict__ sb3,
    const float* __restrict__ ub0, const float* __restrict__ ub1,
    const float* __restrict__ ub2, const float* __restrict__ ub3,
    float* __restrict__ out)
{
    int bid = blockIdx.x;
    {   // bijective XCD-aware swizzle (same-speaker blocks -> same XCD L2)
        int nwg = gridDim.x, q8 = nwg >> 3, r8 = nwg & 7;
        int x = bid & 7, p = bid >> 3;
        bid = (x < r8 ? x * (q8 + 1) : r8 * (q8 + 1) + (x - r8) * q8) + p;
    }
    if (bid >= ws[WS_BLK + NS]) return;

    int s = 0;
    #pragma unroll
    for (int q = 0; q < NS - 1; ++q)
        if (bid >= ws[WS_BLK + q + 1]) s = q + 1;
    const int loc  = bid - ws[WS_BLK + s];
    int nval = ws[WS_CNT + s] - loc * RB64;
    if (nval > RB64) nval = RB64;
    const int base = ws[WS_SEG + s] + loc * RB64;

    __shared__ ushort act[2][32][64][8];

    const int t = threadIdx.x, w = t >> 6, l = t & 63;
    const int lc = l & 15, lh = l >> 4;
    const int nt0 = w * 2;                 // 2 nt tiles per wave (mid layers)

    // stage z transposed into frag layout (k 0..15 real, 16..31 zero)
    if (t < 256) {
        int row = t >> 2, q = t & 3;
        int gb  = ws[WS_IDX + base + row];
        if (row >= nval) gb = 0;
        float4 zv = *(const float4*)(z + (long)gb * LAT + q * 4);
        ushort4 pv; pv.x = f2bf(zv.x); pv.y = f2bf(zv.y); pv.z = f2bf(zv.z); pv.w = f2bf(zv.w);
        *(ushort4*)&act[0][q >> 1][row][(q & 1) * 4] = pv;
        ushort4 zr; zr.x = zr.y = zr.z = zr.w = 0;
        *(ushort4*)&act[0][2 + (q >> 1)][row][(q & 1) * 4] = zr;
    }
    __syncthreads();

    // ---- L0: K=32 (padded), nt {2w,2w+1}, 4 row-tiles ----
    {
        f32x4 acc[2][4];
        #pragma unroll
        for (int q = 0; q < 2; ++q) {
            float4 bv = *(const float4*)(sb0 + (nt0 + q) * 16 + lh * 4);
            #pragma unroll
            for (int rt = 0; rt < 4; ++rt) acc[q][rt] = (f32x4){bv.x, bv.y, bv.z, bv.w};
        }
        bf16x8 Wf[2];
        #pragma unroll
        for (int q = 0; q < 2; ++q)
            Wf[q] = *(const bf16x8*)(wgt + ((nt0 + q) * 64 + l) * 8);
        #pragma unroll
        for (int rt = 0; rt < 4; ++rt) {
            bf16x8 av = *(const bf16x8*)&act[0][lh][rt * 16 + lc][0];
            #pragma unroll
            for (int q = 0; q < 2; ++q)
                acc[q][rt] = __builtin_amdgcn_mfma_f32_16x16x32_bf16(Wf[q], av, acc[q][rt], 0, 0, 0);
        }
        #pragma unroll
        for (int q = 0; q < 2; ++q) {
            int n0 = (nt0 + q) * 16 + lh * 4;
            #pragma unroll
            for (int rt = 0; rt < 4; ++rt) {
                ushort4 u;
                u.x = f2bf(fmaxf(acc[q][rt][0], 0.f));
                u.y = f2bf(fmaxf(acc[q][rt][1], 0.f));
                u.z = f2bf(fmaxf(acc[q][rt][2], 0.f));
                u.w = f2bf(fmaxf(acc[q][rt][3], 0.f));
                *(ushort4*)&act[1][n0 >> 3][rt * 16 + lc][n0 & 7] = u;
            }
        }
    }
    __syncthreads();

    auto midlayer = [&](const ushort* __restrict__ wf, const float* __restrict__ bs, int src) {
        const int dst = src ^ 1;
        f32x4 acc[2][4];
        #pragma unroll
        for (int q = 0; q < 2; ++q) {
            float4 bv = *(const float4*)(bs + (nt0 + q) * 16 + lh * 4);
            #pragma unroll
            for (int rt = 0; rt < 4; ++rt) acc[q][rt] = (f32x4){bv.x, bv.y, bv.z, bv.w};
        }
        bf16x8 Bc[2], Bn[2];
        #pragma unroll
        for (int q = 0; q < 2; ++q)
            Bc[q] = *(const bf16x8*)(wf + ((nt0 + q) * 64 + l) * 8);
        #pragma unroll
        for (int kb = 0; kb < 8; ++kb) {
            if (kb < 7) {
                #pragma unroll
                for (int q = 0; q < 2; ++q)
                    Bn[q] = *(const bf16x8*)(wf + (((kb + 1) * 16 + nt0 + q) * 64 + l) * 8);
            }
            #pragma unroll
            for (int rt = 0; rt < 4; ++rt) {
                bf16x8 av = *(const bf16x8*)&act[src][kb * 4 + lh][rt * 16 + lc][0];
                #pragma unroll
                for (int q = 0; q < 2; ++q)
                    acc[q][rt] = __builtin_amdgcn_mfma_f32_16x16x32_bf16(Bc[q], av, acc[q][rt], 0, 0, 0);
            }
            #pragma unroll
            for (int q = 0; q < 2; ++q) Bc[q] = Bn[q];
        }
        #pragma unroll
        for (int q = 0; q < 2; ++q) {
            int n0 = (nt0 + q) * 16 + lh * 4;
            #pragma unroll
            for (int rt = 0; rt < 4; ++rt) {
                ushort4 u;
                u.x = f2bf(fmaxf(acc[q][rt][0], 0.f));
                u.y = f2bf(fmaxf(acc[q][rt][1], 0.f));
                u.z = f2bf(fmaxf(acc[q][rt][2], 0.f));
                u.w = f2bf(fmaxf(acc[q][rt][3], 0.f));
                *(ushort4*)&act[dst][n0 >> 3][rt * 16 + lc][n0 & 7] = u;
            }
        }
        __syncthreads();
    };

    midlayer(wgt + 8192,   sb1, 1);
    midlayer(wgt + 73728,  sb2, 0);
    midlayer(wgt + 139264, sb3, 1);
    const long sbse = 204800 + (long)s * 212992;
    midlayer(wgt + sbse,          ub0 + s * HID, 0);
    midlayer(wgt + sbse + 65536,  ub1 + s * HID, 1);
    midlayer(wgt + sbse + 131072, ub2 + s * HID, 0);

    // ---- final: act[1] x uw3 -> out (no relu). wave: nt=w&3, row-half=w>>2 ----
    {
        const ushort* wf = wgt + sbse + 196608;
        const float*  bs = ub3 + s * STY;
        const int nt = w & 3, wr = w >> 2;
        const int n0 = nt * 16 + lh * 4;
        f32x4 acc[2];
        {
            float4 bv = *(const float4*)(bs + n0);
            acc[0] = (f32x4){bv.x, bv.y, bv.z, bv.w};
            acc[1] = acc[0];
        }
        bf16x8 Bc = *(const bf16x8*)(wf + (nt * 64 + l) * 8);
        bf16x8 Bn;
        #pragma unroll
        for (int kb = 0; kb < 8; ++kb) {
            if (kb < 7) Bn = *(const bf16x8*)(wf + (((kb + 1) * 4 + nt) * 64 + l) * 8);
            #pragma unroll
            for (int rtl = 0; rtl < 2; ++rtl) {
                int rt = wr * 2 + rtl;
                bf16x8 av = *(const bf16x8*)&act[1][kb * 4 + lh][rt * 16 + lc][0];
                acc[rtl] = __builtin_amdgcn_mfma_f32_16x16x32_bf16(Bc, av, acc[rtl], 0, 0, 0);
            }
            Bc = Bn;
        }
        #pragma unroll
        for (int rtl = 0; rtl < 2; ++rtl) {
            int row = (wr * 2 + rtl) * 16 + lc;
            if (row < nval) {
                int gb = ws[WS_IDX + base + row];
                float4 o = make_float4(acc[rtl][0], acc[rtl][1], acc[rtl][2], acc[rtl][3]);
                *(float4*)(out + (long)gb * STY + n0) = o;
            }
        }
    }
}

// ================= fp32 fallback (RB=16) =================
#define FMA16(wv_, hv_) do { \
    acc[0][0] = fmaf(hv_.x, wv_.x, acc[0][0]); \
    acc[0][1] = fmaf(hv_.y, wv_.x, acc[0][1]); \
    acc[0][2] = fmaf(hv_.z, wv_.x, acc[0][2]); \
    acc[0][3] = fmaf(hv_.w, wv_.x, acc[0][3]); \
    acc[1][0] = fmaf(hv_.x, wv_.y, acc[1][0]); \
    acc[1][1] = fmaf(hv_.y, wv_.y, acc[1][1]); \
    acc[1][2] = fmaf(hv_.z, wv_.y, acc[1][2]); \
    acc[1][3] = fmaf(hv_.w, wv_.y, acc[1][3]); \
    acc[2][0] = fmaf(hv_.x, wv_.z, acc[2][0]); \
    acc[2][1] = fmaf(hv_.y, wv_.z, acc[2][1]); \
    acc[2][2] = fmaf(hv_.z, wv_.z, acc[2][2]); \
    acc[2][3] = fmaf(hv_.w, wv_.z, acc[2][3]); \
    acc[3][0] = fmaf(hv_.x, wv_.w, acc[3][0]); \
    acc[3][1] = fmaf(hv_.y, wv_.w, acc[3][1]); \
    acc[3][2] = fmaf(hv_.z, wv_.w, acc[3][2]); \
    acc[3][3] = fmaf(hv_.w, wv_.w, acc[3][3]); \
} while (0)

__global__ __launch_bounds__(256, 3) void k_main_f32(
    const float* __restrict__ z,
    const int* __restrict__ ws,
    const float* __restrict__ sw0, const float* __restrict__ sb0,
    const float* __restrict__ sw1, const float* __restrict__ sb1,
    const float* __restrict__ sw2, const float* __restrict__ sb2,
    const float* __restrict__ sw3, const float* __restrict__ sb3,
    const float* __restrict__ uw0, const float* __restrict__ ub0,
    const float* __restrict__ uw1, const float* __restrict__ ub1,
    const float* __restrict__ uw2, const float* __restrict__ ub2,
    const float* __restrict__ uw3, const float* __restrict__ ub3,
    float* __restrict__ out)
{
    const int bid = blockIdx.x;
    if (bid >= ws[WS_BLK + NS]) return;
    int s = 0;
    #pragma unroll
    for (int q = 0; q < NS - 1; ++q)
        if (bid >= ws[WS_BLK + q + 1]) s = q + 1;
    const int loc  = bid - ws[WS_BLK + s];
    int nval = ws[WS_CNT + s] - loc * RB;
    if (nval > RB) nval = RB;
    const int base = ws[WS_SEG + s] + loc * RB;

    __shared__ int bidx[RB];
    __shared__ __align__(16) float zt[LAT][PAD];
    __shared__ __align__(16) float ht[2][HID][PAD];

    const int t = threadIdx.x;
    if (t < RB) {
        int gb = ws[WS_IDX + base + t];
        bidx[t] = (t < nval) ? gb : 0;
    }
    __syncthreads();
    { int r = t & (RB - 1), k = t >> 4; zt[k][r] = z[bidx[r] * LAT + k]; }
    __syncthreads();

    const int cg = t & 63, wvi = t >> 6, c0 = cg * 4, r0 = wvi * 4;
    float acc[4][4];
    {
        float4 bv = *(const float4*)(sb0 + c0);
        #pragma unroll
        for (int ri = 0; ri < 4; ++ri) { acc[0][ri] = bv.x; acc[1][ri] = bv.y; acc[2][ri] = bv.z; acc[3][ri] = bv.w; }
        #pragma unroll
        for (int k = 0; k < LAT; ++k) {
            float4 wv = *(const float4*)(sw0 + k * HID + c0);
            float4 hv = *(const float4*)(&zt[k][r0]);
            FMA16(wv, hv);
        }
        #pragma unroll
        for (int ci = 0; ci < 4; ++ci) {
            float4 v;
            v.x = fmaxf(acc[ci][0], 0.f); v.y = fmaxf(acc[ci][1], 0.f);
            v.z = fmaxf(acc[ci][2], 0.f); v.w = fmaxf(acc[ci][3], 0.f);
            *(float4*)&ht[0][c0 + ci][r0] = v;
        }
    }
    __syncthreads();

    auto midlayer = [&](const float* __restrict__ W, const float* __restrict__ bs, int src) {
        float4 bv = *(const float4*)(bs + c0);
        #pragma unroll
        for (int ri = 0; ri < 4; ++ri) { acc[0][ri] = bv.x; acc[1][ri] = bv.y; acc[2][ri] = bv.z; acc[3][ri] = bv.w; }
        #pragma unroll 4
        for (int k = 0; k < HID; ++k) {
            float4 wv = *(const float4*)(W + k * HID + c0);
            float4 hv = *(const float4*)(&ht[src][k][r0]);
            FMA16(wv, hv);
        }
        const int dst = src ^ 1;
        #pragma unroll
        for (int ci = 0; ci < 4; ++ci) {
            float4 v;
            v.x = fmaxf(acc[ci][0], 0.f); v.y = fmaxf(acc[ci][1], 0.f);
            v.z = fmaxf(acc[ci][2], 0.f); v.w = fmaxf(acc[ci][3], 0.f);
            *(float4*)&ht[dst][c0 + ci][r0] = v;
        }
    };

    midlayer(sw1, sb1, 0); __syncthreads();
    midlayer(sw2, sb2, 1); __syncthreads();
    midlayer(sw3, sb3, 0); __syncthreads();
    const long so = (long)s;
    midlayer(uw0 + so * HID * HID, ub0 + so * HID, 1); __syncthreads();
    midlayer(uw1 + so * HID * HID, ub1 + so * HID, 0); __syncthreads();
    midlayer(uw2 + so * HID * HID, ub2 + so * HID, 1); __syncthreads();

    {
        const float* W  = uw3 + so * HID * STY;
        const float* bs = ub3 + so * STY;
        const int c64 = (t & 15) * 4, rr = t >> 4;
        float4 bv = *(const float4*)(bs + c64);
        float a0 = bv.x, a1 = bv.y, a2 = bv.z, a3 = bv.w;
        #pragma unroll 4
        for (int k = 0; k < HID; ++k) {
            float4 wv = *(const float4*)(W + k * STY + c64);
            float  hv = ht[0][k][rr];
            a0 = fmaf(hv, wv.x, a0); a1 = fmaf(hv, wv.y, a1);
            a2 = fmaf(hv, wv.z, a2); a3 = fmaf(hv, wv.w, a3);
        }
        if (rr < nval) *(float4*)(out + (long)bidx[rr] * STY + c64) = make_float4(a0, a1, a2, a3);
    }
}

extern "C" void kernel_launch(void* const* d_in, const int* in_sizes, int n_in,
                              void* d_out, int out_size, void* d_ws, size_t ws_size,
                              hipStream_t stream) {
    const float* z   = (const float*)d_in[0];
    const int*   y   = (const int*)  d_in[1];
    const float* sw0 = (const float*)d_in[2];  const float* sb0 = (const float*)d_in[3];
    const float* sw1 = (const float*)d_in[4];  const float* sb1 = (const float*)d_in[5];
    const float* sw2 = (const float*)d_in[6];  const float* sb2 = (const float*)d_in[7];
    const float* sw3 = (const float*)d_in[8];  const float* sb3 = (const float*)d_in[9];
    const float* uw0 = (const float*)d_in[10]; const float* ub0 = (const float*)d_in[11];
    const float* uw1 = (const float*)d_in[12]; const float* ub1 = (const float*)d_in[13];
    const float* uw2 = (const float*)d_in[14]; const float* ub2 = (const float*)d_in[15];
    const float* uw3 = (const float*)d_in[16]; const float* ub3 = (const float*)d_in[17];
    float* out = (float*)d_out;
    int*   ws  = (int*)d_ws;

    const size_t req = (size_t)WGT_OFF_EL * 2 + (size_t)TOT_WEL * 2;
    const bool bfp = (ws_size >= req);
    const int  rb  = bfp ? RB64 : RB;

    k_blkhist<<<NBK, 256, 0, stream>>>(y, ws);
    k_off2   <<<1, 640, 0, stream>>>(ws, rb);
    k_scat2  <<<NBK, 256, 0, stream>>>(y, ws);

    if (bfp) {
        ushort* wgt = (ushort*)d_ws + WGT_OFF_EL;
        k_conv<<<N_CHUNK / 4, 256, 0, stream>>>(sw0, sw1, sw2, sw3, uw0, uw1, uw2, uw3, wgt);
        const int nblocks = B_TOT / RB64 + NS;
        k_main_bf<<<nblocks, 512, 0, stream>>>(z, ws, wgt,
            sb0, sb1, sb2, sb3, ub0, ub1, ub2, ub3, out);
    } else {
        const int nblocks = B_TOT / RB + NS;
        k_main_f32<<<nblocks, 256, 0, stream>>>(z, ws,
            sw0, sb0, sw1, sb1, sw2, sb2, sw3, sb3,
            uw0, ub0, uw1, ub1, uw2, ub2, uw3, ub3, out);
    }
}

// Round 6
// 41.877 us; speedup vs baseline: 10.2131x; 1.1106x over previous
//
#include <hip/hip_runtime.h>

#define B_TOT 16384
#define LAT   16
#define HID   256
#define STY   64
#define NS    10
#define RB    16      // rows per block (fp32 fallback path)
#define RB64  64      // rows per block (bf16 MFMA path)
#define PAD   20
#define NBK   64      // histogram blocks = B_TOT/256

// workspace layout (ints)
#define WS_CNT   0                       // 10: total count per speaker
#define WS_SEG   16                      // 10: padded segment start per speaker
#define WS_BLK   32                      // 11: main-kernel block offsets
#define WS_BCNT  64                      // 64*10: per-block histogram
#define WS_IDX   (WS_BCNT + NBK*NS)      // sorted row indices (+pad garbage, clamped)
#define IDX_CAP  (B_TOT + NS*RB64)
#define WS_INTS  (WS_IDX + IDX_CAP)
#define WGT_OFF_EL (((WS_INTS*4 + 255)/256)*128 + 384)  // ushort offset (keeps old value-class alignment)
#define TOT_WEL  2334720                 // total bf16 weight elements
#define N_CHUNK  4560                    // TOT_WEL / 512

typedef __attribute__((ext_vector_type(8))) short bf16x8;
typedef __attribute__((ext_vector_type(4))) float f32x4;

static __device__ __forceinline__ ushort f2bf(float x) {
    union { float f; unsigned u; } c; c.f = x;
    unsigned u = c.u;
    unsigned r = u + 0x7FFFu + ((u >> 16) & 1u);   // RTNE
    return (ushort)(r >> 16);
}

// ---- standalone per-block histogram (fp32 fallback path only) ----
__global__ __launch_bounds__(256) void k_blkhist(const int* __restrict__ y, int* __restrict__ ws) {
    __shared__ int h[NS];
    int t = threadIdx.x;
    if (t < NS) h[t] = 0;
    __syncthreads();
    atomicAdd(&h[y[blockIdx.x * 256 + t]], 1);
    __syncthreads();
    if (t < NS) ws[WS_BCNT + blockIdx.x * NS + t] = h[t];
}

// ---- fused prep: per-block redundant scan + scatter (one launch) ----
// Each of the 64 blocks recomputes the global scan from WS_BCNT (cheap, L2-hot),
// derives its own absolute cursors, scatters its 256 row indices via LDS atomics.
__global__ __launch_bounds__(256) void k_prep2(const int* __restrict__ y, int* __restrict__ ws, int rb) {
    __shared__ int tot_sh[NS], excl_sh[NS], off_sh[NS];
    const int t = threadIdx.x, wv = t >> 6, l = t & 63;
    const int myb = blockIdx.x;

    // wave wv handles speakers wv, wv+4, wv+8; lane l = histogram block l
    for (int s = wv; s < NS; s += 4) {
        int c = ws[WS_BCNT + l * NS + s];
        int inc = c;
        #pragma unroll
        for (int o = 1; o < 64; o <<= 1) {
            int v = __shfl_up(inc, o, 64);
            if (l >= o) inc += v;
        }
        int tot = __shfl(inc, 63, 64);
        int exc = __shfl(inc, myb, 64) - __shfl(c, myb, 64);  // sum of counts in blocks < myb
        if (l == 0) { tot_sh[s] = tot; excl_sh[s] = exc; }
    }
    __syncthreads();
    if (t < NS) {
        int ab = 0, ae = 0;
        for (int q = 0; q < t; ++q) {
            int cq = tot_sh[q];
            int nb = (cq + rb - 1) / rb;
            ab += nb; ae += nb * rb;
        }
        off_sh[t] = ae + excl_sh[t];
        if (myb == 0) {
            ws[WS_CNT + t] = tot_sh[t];
            ws[WS_SEG + t] = ae;
            ws[WS_BLK + t] = ab;
        }
    }
    if (myb == 0 && t == 0) {
        int ab = 0;
        for (int q = 0; q < NS; ++q) ab += (tot_sh[q] + rb - 1) / rb;
        ws[WS_BLK + NS] = ab;
    }
    __syncthreads();
    int b = myb * 256 + t;
    int p = atomicAdd(&off_sh[y[b]], 1);
    ws[WS_IDX + p] = b;
}

// ---- convert fp32 weights -> bf16 frag-linear layout; blocks<64 also histogram y ----
__global__ __launch_bounds__(256) void k_conv(
    const float* __restrict__ sw0, const float* __restrict__ sw1,
    const float* __restrict__ sw2, const float* __restrict__ sw3,
    const float* __restrict__ uw0, const float* __restrict__ uw1,
    const float* __restrict__ uw2, const float* __restrict__ uw3,
    ushort* __restrict__ wgt,
    const int* __restrict__ y, int* __restrict__ ws)
{
    __shared__ float tile[4][32][18];
    __shared__ int h[NS];

    // fused histogram (blocks 0..63)
    if (blockIdx.x < NBK) {
        int t = threadIdx.x;
        if (t < NS) h[t] = 0;
        __syncthreads();
        atomicAdd(&h[y[blockIdx.x * 256 + t]], 1);
        __syncthreads();
        if (t < NS) ws[WS_BCNT + blockIdx.x * NS + t] = h[t];
    }

    int wid = blockIdx.x * 4 + (threadIdx.x >> 6);
    int wv  = threadIdx.x >> 6;
    int l   = threadIdx.x & 63;
    int lc  = l & 15, lh = l >> 4;

    const float* src; int Ksrc, N, kb, nt;
    if (wid < 16) {
        src = sw0; Ksrc = LAT; N = 256; kb = 0; nt = wid;
    } else if (wid < 400) {
        int c = wid - 16; int ly = c >> 7; int r = c & 127;
        src = (ly == 0 ? sw1 : ly == 1 ? sw2 : sw3);
        Ksrc = 256; N = 256; kb = r >> 4; nt = r & 15;
    } else {
        int c = wid - 400; int s = c / 416; int r = c % 416;
        if (r < 384) {
            int ly = r >> 7; int rr = r & 127;
            src = (ly == 0 ? uw0 : ly == 1 ? uw1 : uw2) + (long)s * 65536;
            Ksrc = 256; N = 256; kb = rr >> 4; nt = rr & 15;
        } else {
            int rr = r - 384;
            src = uw3 + (long)s * 16384;
            Ksrc = 256; N = STY; kb = rr >> 2; nt = rr & 3;
        }
    }

    #pragma unroll
    for (int it = 0; it < 2; ++it) {
        int r = it * 16 + (l >> 2);
        int k = kb * 32 + r;
        float4 v = make_float4(0.f, 0.f, 0.f, 0.f);
        if (k < Ksrc) v = *(const float4*)(src + (long)k * N + nt * 16 + (l & 3) * 4);
        int c = (l & 3) * 4;
        tile[wv][r][c] = v.x; tile[wv][r][c + 1] = v.y;
        tile[wv][r][c + 2] = v.z; tile[wv][r][c + 3] = v.w;
    }
    __syncthreads();

    ushort v[8];
    #pragma unroll
    for (int j = 0; j < 8; ++j) v[j] = f2bf(tile[wv][lh * 8 + j][lc]);
    uint4 o;
    o.x = (unsigned)v[0] | ((unsigned)v[1] << 16);
    o.y = (unsigned)v[2] | ((unsigned)v[3] << 16);
    o.z = (unsigned)v[4] | ((unsigned)v[5] << 16);
    o.w = (unsigned)v[6] | ((unsigned)v[7] << 16);
    *(uint4*)(wgt + (long)wid * 512 + l * 8) = o;
}

// ---- bf16 MFMA main kernel (v5 structure, unchanged) ----
__global__ __launch_bounds__(512, 4) void k_main_bf(
    const float* __restrict__ z, const int* __restrict__ ws,
    const ushort* __restrict__ wgt,
    const float* __restrict__ sb0, const float* __restrict__ sb1,
    const float* __restrict__ sb2, const float* __restrict__ sb3,
    const float* __restrict__ ub0, const float* __restrict__ ub1,
    const float* __restrict__ ub2, const float* __restrict__ ub3,
    float* __restrict__ out)
{
    int bid = blockIdx.x;
    {   // bijective XCD-aware swizzle (same-speaker blocks -> same XCD L2)
        int nwg = gridDim.x, q8 = nwg >> 3, r8 = nwg & 7;
        int x = bid & 7, p = bid >> 3;
        bid = (x < r8 ? x * (q8 + 1) : r8 * (q8 + 1) + (x - r8) * q8) + p;
    }
    if (bid >= ws[WS_BLK + NS]) return;

    int s = 0;
    #pragma unroll
    for (int q = 0; q < NS - 1; ++q)
        if (bid >= ws[WS_BLK + q + 1]) s = q + 1;
    const int loc  = bid - ws[WS_BLK + s];
    int nval = ws[WS_CNT + s] - loc * RB64;
    if (nval > RB64) nval = RB64;
    const int base = ws[WS_SEG + s] + loc * RB64;

    __shared__ ushort act[2][32][64][8];

    const int t = threadIdx.x, w = t >> 6, l = t & 63;
    const int lc = l & 15, lh = l >> 4;
    const int nt0 = w * 2;

    if (t < 256) {
        int row = t >> 2, q = t & 3;
        int gb  = ws[WS_IDX + base + row];
        if (row >= nval) gb = 0;
        float4 zv = *(const float4*)(z + (long)gb * LAT + q * 4);
        ushort4 pv; pv.x = f2bf(zv.x); pv.y = f2bf(zv.y); pv.z = f2bf(zv.z); pv.w = f2bf(zv.w);
        *(ushort4*)&act[0][q >> 1][row][(q & 1) * 4] = pv;
        ushort4 zr; zr.x = zr.y = zr.z = zr.w = 0;
        *(ushort4*)&act[0][2 + (q >> 1)][row][(q & 1) * 4] = zr;
    }
    __syncthreads();

    // ---- L0 ----
    {
        f32x4 acc[2][4];
        #pragma unroll
        for (int q = 0; q < 2; ++q) {
            float4 bv = *(const float4*)(sb0 + (nt0 + q) * 16 + lh * 4);
            #pragma unroll
            for (int rt = 0; rt < 4; ++rt) acc[q][rt] = (f32x4){bv.x, bv.y, bv.z, bv.w};
        }
        bf16x8 Wf[2];
        #pragma unroll
        for (int q = 0; q < 2; ++q)
            Wf[q] = *(const bf16x8*)(wgt + ((nt0 + q) * 64 + l) * 8);
        #pragma unroll
        for (int rt = 0; rt < 4; ++rt) {
            bf16x8 av = *(const bf16x8*)&act[0][lh][rt * 16 + lc][0];
            #pragma unroll
            for (int q = 0; q < 2; ++q)
                acc[q][rt] = __builtin_amdgcn_mfma_f32_16x16x32_bf16(Wf[q], av, acc[q][rt], 0, 0, 0);
        }
        #pragma unroll
        for (int q = 0; q < 2; ++q) {
            int n0 = (nt0 + q) * 16 + lh * 4;
            #pragma unroll
            for (int rt = 0; rt < 4; ++rt) {
                ushort4 u;
                u.x = f2bf(fmaxf(acc[q][rt][0], 0.f));
                u.y = f2bf(fmaxf(acc[q][rt][1], 0.f));
                u.z = f2bf(fmaxf(acc[q][rt][2], 0.f));
                u.w = f2bf(fmaxf(acc[q][rt][3], 0.f));
                *(ushort4*)&act[1][n0 >> 3][rt * 16 + lc][n0 & 7] = u;
            }
        }
    }
    __syncthreads();

    auto midlayer = [&](const ushort* __restrict__ wf, const float* __restrict__ bs, int src) {
        const int dst = src ^ 1;
        f32x4 acc[2][4];
        #pragma unroll
        for (int q = 0; q < 2; ++q) {
            float4 bv = *(const float4*)(bs + (nt0 + q) * 16 + lh * 4);
            #pragma unroll
            for (int rt = 0; rt < 4; ++rt) acc[q][rt] = (f32x4){bv.x, bv.y, bv.z, bv.w};
        }
        bf16x8 Bc[2], Bn[2];
        #pragma unroll
        for (int q = 0; q < 2; ++q)
            Bc[q] = *(const bf16x8*)(wf + ((nt0 + q) * 64 + l) * 8);
        #pragma unroll
        for (int kb = 0; kb < 8; ++kb) {
            if (kb < 7) {
                #pragma unroll
                for (int q = 0; q < 2; ++q)
                    Bn[q] = *(const bf16x8*)(wf + (((kb + 1) * 16 + nt0 + q) * 64 + l) * 8);
            }
            #pragma unroll
            for (int rt = 0; rt < 4; ++rt) {
                bf16x8 av = *(const bf16x8*)&act[src][kb * 4 + lh][rt * 16 + lc][0];
                #pragma unroll
                for (int q = 0; q < 2; ++q)
                    acc[q][rt] = __builtin_amdgcn_mfma_f32_16x16x32_bf16(Bc[q], av, acc[q][rt], 0, 0, 0);
            }
            #pragma unroll
            for (int q = 0; q < 2; ++q) Bc[q] = Bn[q];
        }
        #pragma unroll
        for (int q = 0; q < 2; ++q) {
            int n0 = (nt0 + q) * 16 + lh * 4;
            #pragma unroll
            for (int rt = 0; rt < 4; ++rt) {
                ushort4 u;
                u.x = f2bf(fmaxf(acc[q][rt][0], 0.f));
                u.y = f2bf(fmaxf(acc[q][rt][1], 0.f));
                u.z = f2bf(fmaxf(acc[q][rt][2], 0.f));
                u.w = f2bf(fmaxf(acc[q][rt][3], 0.f));
                *(ushort4*)&act[dst][n0 >> 3][rt * 16 + lc][n0 & 7] = u;
            }
        }
        __syncthreads();
    };

    midlayer(wgt + 8192,   sb1, 1);
    midlayer(wgt + 73728,  sb2, 0);
    midlayer(wgt + 139264, sb3, 1);
    const long sbse = 204800 + (long)s * 212992;
    midlayer(wgt + sbse,          ub0 + s * HID, 0);
    midlayer(wgt + sbse + 65536,  ub1 + s * HID, 1);
    midlayer(wgt + sbse + 131072, ub2 + s * HID, 0);

    // ---- final: act[1] x uw3 -> out (no relu). wave: nt=w&3, row-half=w>>2 ----
    {
        const ushort* wf = wgt + sbse + 196608;
        const float*  bs = ub3 + s * STY;
        const int nt = w & 3, wr = w >> 2;
        const int n0 = nt * 16 + lh * 4;
        f32x4 acc[2];
        {
            float4 bv = *(const float4*)(bs + n0);
            acc[0] = (f32x4){bv.x, bv.y, bv.z, bv.w};
            acc[1] = acc[0];
        }
        bf16x8 Bc = *(const bf16x8*)(wf + (nt * 64 + l) * 8);
        bf16x8 Bn;
        #pragma unroll
        for (int kb = 0; kb < 8; ++kb) {
            if (kb < 7) Bn = *(const bf16x8*)(wf + (((kb + 1) * 4 + nt) * 64 + l) * 8);
            #pragma unroll
            for (int rtl = 0; rtl < 2; ++rtl) {
                int rt = wr * 2 + rtl;
                bf16x8 av = *(const bf16x8*)&act[1][kb * 4 + lh][rt * 16 + lc][0];
                acc[rtl] = __builtin_amdgcn_mfma_f32_16x16x32_bf16(Bc, av, acc[rtl], 0, 0, 0);
            }
            Bc = Bn;
        }
        #pragma unroll
        for (int rtl = 0; rtl < 2; ++rtl) {
            int row = (wr * 2 + rtl) * 16 + lc;
            if (row < nval) {
                int gb = ws[WS_IDX + base + row];
                float4 o = make_float4(acc[rtl][0], acc[rtl][1], acc[rtl][2], acc[rtl][3]);
                *(float4*)(out + (long)gb * STY + n0) = o;
            }
        }
    }
}

// ================= fp32 fallback (RB=16) =================
#define FMA16(wv_, hv_) do { \
    acc[0][0] = fmaf(hv_.x, wv_.x, acc[0][0]); \
    acc[0][1] = fmaf(hv_.y, wv_.x, acc[0][1]); \
    acc[0][2] = fmaf(hv_.z, wv_.x, acc[0][2]); \
    acc[0][3] = fmaf(hv_.w, wv_.x, acc[0][3]); \
    acc[1][0] = fmaf(hv_.x, wv_.y, acc[1][0]); \
    acc[1][1] = fmaf(hv_.y, wv_.y, acc[1][1]); \
    acc[1][2] = fmaf(hv_.z, wv_.y, acc[1][2]); \
    acc[1][3] = fmaf(hv_.w, wv_.y, acc[1][3]); \
    acc[2][0] = fmaf(hv_.x, wv_.z, acc[2][0]); \
    acc[2][1] = fmaf(hv_.y, wv_.z, acc[2][1]); \
    acc[2][2] = fmaf(hv_.z, wv_.z, acc[2][2]); \
    acc[2][3] = fmaf(hv_.w, wv_.z, acc[2][3]); \
    acc[3][0] = fmaf(hv_.x, wv_.w, acc[3][0]); \
    acc[3][1] = fmaf(hv_.y, wv_.w, acc[3][1]); \
    acc[3][2] = fmaf(hv_.z, wv_.w, acc[3][2]); \
    acc[3][3] = fmaf(hv_.w, wv_.w, acc[3][3]); \
} while (0)

__global__ __launch_bounds__(256, 3) void k_main_f32(
    const float* __restrict__ z,
    const int* __restrict__ ws,
    const float* __restrict__ sw0, const float* __restrict__ sb0,
    const float* __restrict__ sw1, const float* __restrict__ sb1,
    const float* __restrict__ sw2, const float* __restrict__ sb2,
    const float* __restrict__ sw3, const float* __restrict__ sb3,
    const float* __restrict__ uw0, const float* __restrict__ ub0,
    const float* __restrict__ uw1, const float* __restrict__ ub1,
    const float* __restrict__ uw2, const float* __restrict__ ub2,
    const float* __restrict__ uw3, const float* __restrict__ ub3,
    float* __restrict__ out)
{
    const int bid = blockIdx.x;
    if (bid >= ws[WS_BLK + NS]) return;
    int s = 0;
    #pragma unroll
    for (int q = 0; q < NS - 1; ++q)
        if (bid >= ws[WS_BLK + q + 1]) s = q + 1;
    const int loc  = bid - ws[WS_BLK + s];
    int nval = ws[WS_CNT + s] - loc * RB;
    if (nval > RB) nval = RB;
    const int base = ws[WS_SEG + s] + loc * RB;

    __shared__ int bidx[RB];
    __shared__ __align__(16) float zt[LAT][PAD];
    __shared__ __align__(16) float ht[2][HID][PAD];

    const int t = threadIdx.x;
    if (t < RB) {
        int gb = ws[WS_IDX + base + t];
        bidx[t] = (t < nval) ? gb : 0;
    }
    __syncthreads();
    { int r = t & (RB - 1), k = t >> 4; zt[k][r] = z[bidx[r] * LAT + k]; }
    __syncthreads();

    const int cg = t & 63, wvi = t >> 6, c0 = cg * 4, r0 = wvi * 4;
    float acc[4][4];
    {
        float4 bv = *(const float4*)(sb0 + c0);
        #pragma unroll
        for (int ri = 0; ri < 4; ++ri) { acc[0][ri] = bv.x; acc[1][ri] = bv.y; acc[2][ri] = bv.z; acc[3][ri] = bv.w; }
        #pragma unroll
        for (int k = 0; k < LAT; ++k) {
            float4 wv = *(const float4*)(sw0 + k * HID + c0);
            float4 hv = *(const float4*)(&zt[k][r0]);
            FMA16(wv, hv);
        }
        #pragma unroll
        for (int ci = 0; ci < 4; ++ci) {
            float4 v;
            v.x = fmaxf(acc[ci][0], 0.f); v.y = fmaxf(acc[ci][1], 0.f);
            v.z = fmaxf(acc[ci][2], 0.f); v.w = fmaxf(acc[ci][3], 0.f);
            *(float4*)&ht[0][c0 + ci][r0] = v;
        }
    }
    __syncthreads();

    auto midlayer = [&](const float* __restrict__ W, const float* __restrict__ bs, int src) {
        float4 bv = *(const float4*)(bs + c0);
        #pragma unroll
        for (int ri = 0; ri < 4; ++ri) { acc[0][ri] = bv.x; acc[1][ri] = bv.y; acc[2][ri] = bv.z; acc[3][ri] = bv.w; }
        #pragma unroll 4
        for (int k = 0; k < HID; ++k) {
            float4 wv = *(const float4*)(W + k * HID + c0);
            float4 hv = *(const float4*)(&ht[src][k][r0]);
            FMA16(wv, hv);
        }
        const int dst = src ^ 1;
        #pragma unroll
        for (int ci = 0; ci < 4; ++ci) {
            float4 v;
            v.x = fmaxf(acc[ci][0], 0.f); v.y = fmaxf(acc[ci][1], 0.f);
            v.z = fmaxf(acc[ci][2], 0.f); v.w = fmaxf(acc[ci][3], 0.f);
            *(float4*)&ht[dst][c0 + ci][r0] = v;
        }
    };

    midlayer(sw1, sb1, 0); __syncthreads();
    midlayer(sw2, sb2, 1); __syncthreads();
    midlayer(sw3, sb3, 0); __syncthreads();
    const long so = (long)s;
    midlayer(uw0 + so * HID * HID, ub0 + so * HID, 1); __syncthreads();
    midlayer(uw1 + so * HID * HID, ub1 + so * HID, 0); __syncthreads();
    midlayer(uw2 + so * HID * HID, ub2 + so * HID, 1); __syncthreads();

    {
        const float* W  = uw3 + so * HID * STY;
        const float* bs = ub3 + so * STY;
        const int c64 = (t & 15) * 4, rr = t >> 4;
        float4 bv = *(const float4*)(bs + c64);
        float a0 = bv.x, a1 = bv.y, a2 = bv.z, a3 = bv.w;
        #pragma unroll 4
        for (int k = 0; k < HID; ++k) {
            float4 wv = *(const float4*)(W + k * STY + c64);
            float  hv = ht[0][k][rr];
            a0 = fmaf(hv, wv.x, a0); a1 = fmaf(hv, wv.y, a1);
            a2 = fmaf(hv, wv.z, a2); a3 = fmaf(hv, wv.w, a3);
        }
        if (rr < nval) *(float4*)(out + (long)bidx[rr] * STY + c64) = make_float4(a0, a1, a2, a3);
    }
}

extern "C" void kernel_launch(void* const* d_in, const int* in_sizes, int n_in,
                              void* d_out, int out_size, void* d_ws, size_t ws_size,
                              hipStream_t stream) {
    const float* z   = (const float*)d_in[0];
    const int*   y   = (const int*)  d_in[1];
    const float* sw0 = (const float*)d_in[2];  const float* sb0 = (const float*)d_in[3];
    const float* sw1 = (const float*)d_in[4];  const float* sb1 = (const float*)d_in[5];
    const float* sw2 = (const float*)d_in[6];  const float* sb2 = (const float*)d_in[7];
    const float* sw3 = (const float*)d_in[8];  const float* sb3 = (const float*)d_in[9];
    const float* uw0 = (const float*)d_in[10]; const float* ub0 = (const float*)d_in[11];
    const float* uw1 = (const float*)d_in[12]; const float* ub1 = (const float*)d_in[13];
    const float* uw2 = (const float*)d_in[14]; const float* ub2 = (const float*)d_in[15];
    const float* uw3 = (const float*)d_in[16]; const float* ub3 = (const float*)d_in[17];
    float* out = (float*)d_out;
    int*   ws  = (int*)d_ws;

    const size_t req = (size_t)WGT_OFF_EL * 2 + (size_t)TOT_WEL * 2;
    const bool bfp = (ws_size >= req);

    if (bfp) {
        ushort* wgt = (ushort*)d_ws + WGT_OFF_EL;
        k_conv <<<N_CHUNK / 4, 256, 0, stream>>>(sw0, sw1, sw2, sw3, uw0, uw1, uw2, uw3, wgt, y, ws);
        k_prep2<<<NBK, 256, 0, stream>>>(y, ws, RB64);
        const int nblocks = B_TOT / RB64 + NS;
        k_main_bf<<<nblocks, 512, 0, stream>>>(z, ws, wgt,
            sb0, sb1, sb2, sb3, ub0, ub1, ub2, ub3, out);
    } else {
        k_blkhist<<<NBK, 256, 0, stream>>>(y, ws);
        k_prep2  <<<NBK, 256, 0, stream>>>(y, ws, RB);
        const int nblocks = B_TOT / RB + NS;
        k_main_f32<<<nblocks, 256, 0, stream>>>(z, ws,
            sw0, sb0, sw1, sb1, sw2, sb2, sw3, sb3,
            uw0, ub0, uw1, ub1, uw2, ub2, uw3, ub3, out);
    }
}